// Round 1
// baseline (457.287 us; speedup 1.0000x reference)
//
#include <hip/hip_runtime.h>

// Fused attention block: x@Wqkv^T -> rotary -> flash attn -> @Wproj^T + b
// B=1 N=2048 DIM=128 HEADS=32 D=256 ROT=64, fp32 in/out, bf16 MFMA internals.

typedef unsigned short u16;
typedef unsigned int u32;
typedef __attribute__((ext_vector_type(8))) u16 u16x8;
typedef __attribute__((ext_vector_type(8))) __bf16 bf16x8;
typedef __attribute__((ext_vector_type(4))) float f32x4;
typedef __attribute__((ext_vector_type(2))) u32 u32x2;

#define DEV static __device__ __forceinline__

DEV u16 f2b(float f) {                 // fp32 -> bf16 RNE
  u32 u = __builtin_bit_cast(u32, f);
  u += 0x7fffu + ((u >> 16) & 1u);
  return (u16)(u >> 16);
}
DEV float b2f(u16 b) {
  u32 u = ((u32)b) << 16;
  return __builtin_bit_cast(float, u);
}
DEV u32 pack2(float a, float b) { return (u32)f2b(a) | ((u32)f2b(b) << 16); }

DEV f32x4 mfma16(u16x8 a, u16x8 b, f32x4 c) {
  return __builtin_amdgcn_mfma_f32_16x16x32_bf16(
      __builtin_bit_cast(bf16x8, a), __builtin_bit_cast(bf16x8, b), c, 0, 0, 0);
}

// XOR swizzle (G4/T2): byte offset within a tile whose rows are rowBytes wide.
DEV int swz(int row, int kelem, int rowBytes) {
  return row * rowBytes + ((kelem * 2) ^ ((row & 7) << 4));
}

// ---------------- kernel 0: fp32 -> bf16 convert ----------------
__global__ __launch_bounds__(256) void k_cvt(const float* __restrict__ src,
                                             u16* __restrict__ dst, int n8) {
  int i = blockIdx.x * 256 + threadIdx.x;
  if (i >= n8) return;
  const float4* s = (const float4*)src;
  float4 a = s[i * 2], b = s[i * 2 + 1];
  u16x8 o;
  o[0] = f2b(a.x); o[1] = f2b(a.y); o[2] = f2b(a.z); o[3] = f2b(a.w);
  o[4] = f2b(b.x); o[5] = f2b(b.y); o[6] = f2b(b.z); o[7] = f2b(b.w);
  *(u16x8*)(dst + (size_t)i * 8) = o;
}

// ---------------- kernel 1: QKV GEMM (M=2048,N=24576,K=128) ----------------
// Q,K written [h][n][256]; V written transposed [h][d][n].
__global__ __launch_bounds__(256) void k_qkv(const u16* __restrict__ xb,
                                             const u16* __restrict__ wb,
                                             u16* __restrict__ qw,
                                             u16* __restrict__ kw,
                                             u16* __restrict__ vw) {
  __shared__ char lds[65536];  // W tile [128][128] @0, x tile [128][128] @32768
  const int tid = threadIdx.x;
  const int rt = blockIdx.x % 192, nt = blockIdx.x / 192;
  const int r0 = rt * 128, n0 = nt * 128;
#pragma unroll
  for (int p = 0; p < 8; ++p) {
    int row = p * 16 + (tid >> 4);
    int k0 = (tid & 15) * 8;
    *(u16x8*)(lds + swz(row, k0, 256)) =
        *(const u16x8*)(wb + (size_t)(r0 + row) * 128 + k0);
    *(u16x8*)(lds + 32768 + swz(row, k0, 256)) =
        *(const u16x8*)(xb + (size_t)(n0 + row) * 128 + k0);
  }
  __syncthreads();
  const int wid = tid >> 6, lane = tid & 63, lq = lane & 15, g = lane >> 4;
  const int wr = wid >> 1, wn = wid & 1;
  const bool isV = (r0 >= 16384);
  f32x4 acc[4][4] = {};
#pragma unroll
  for (int ks = 0; ks < 4; ++ks) {
    u16x8 wa[4], xa[4];
#pragma unroll
    for (int i = 0; i < 4; ++i) {
      int rw = wr * 64 + i * 16 + lq;
      wa[i] = *(const u16x8*)(lds + swz(rw, ks * 32 + g * 8, 256));
      int rx = wn * 64 + i * 16 + lq;
      xa[i] = *(const u16x8*)(lds + 32768 + swz(rx, ks * 32 + g * 8, 256));
    }
    if (!isV) {
#pragma unroll
      for (int i = 0; i < 4; ++i)
#pragma unroll
        for (int j = 0; j < 4; ++j) acc[i][j] = mfma16(wa[i], xa[j], acc[i][j]);
    } else {
#pragma unroll
      for (int i = 0; i < 4; ++i)
#pragma unroll
        for (int j = 0; j < 4; ++j) acc[i][j] = mfma16(xa[j], wa[i], acc[i][j]);
    }
  }
  if (!isV) {
    // D: row = r (4 consecutive per lane), col = n. 4 consecutive d -> 8B store.
#pragma unroll
    for (int i = 0; i < 4; ++i) {
      int rb = r0 + wr * 64 + i * 16 + g * 4;
      u16* dst0 = (rb >= 8192) ? kw : qw;
      int hd = rb & 8191;
      int h = hd >> 8, db = hd & 255;
#pragma unroll
      for (int j = 0; j < 4; ++j) {
        int n = n0 + wn * 64 + j * 16 + lq;
        u32x2 pk;
        pk.x = pack2(acc[i][j][0], acc[i][j][1]);
        pk.y = pack2(acc[i][j][2], acc[i][j][3]);
        *(u32x2*)(dst0 + ((size_t)h * 2048 + n) * 256 + db) = pk;
      }
    }
  } else {
    // D: row = n (4 consecutive per lane), col = d. Write V^T[h][d][n].
#pragma unroll
    for (int i = 0; i < 4; ++i) {
      int rc = r0 - 16384 + wr * 64 + i * 16 + lq;
      int h = rc >> 8, d = rc & 255;
#pragma unroll
      for (int j = 0; j < 4; ++j) {
        int nb = n0 + wn * 64 + j * 16 + g * 4;
        u32x2 pk;
        pk.x = pack2(acc[i][j][0], acc[i][j][1]);
        pk.y = pack2(acc[i][j][2], acc[i][j][3]);
        *(u32x2*)(vw + ((size_t)h * 256 + d) * 2048 + nb) = pk;
      }
    }
  }
}

// ---------------- kernel 2: rotary (in-place on Q,K, first 64 dims) --------
__global__ __launch_bounds__(256) void k_rope(u16* __restrict__ qw,
                                              u16* __restrict__ kw,
                                              const float* __restrict__ fr) {
  int idx = blockIdx.x * 256 + threadIdx.x;  // 2*32*2048*4 = 524288
  int seg = idx & 3;
  int n = (idx >> 2) & 2047;
  int h = (idx >> 13) & 31;
  u16* base = ((idx >> 18) ? kw : qw) + ((size_t)h * 2048 + n) * 256 + seg * 8;
  u16x8 lo = *(const u16x8*)base;
  u16x8 hi = *(const u16x8*)(base + 32);
  const float* f = fr + n * 64 + seg * 8;
  u16x8 nlo, nhi;
#pragma unroll
  for (int e = 0; e < 8; ++e) {
    float fl = f[e], fh = f[e + 32];
    float sl, cl, sh, ch;
    sincosf(fl, &sl, &cl);
    sincosf(fh, &sh, &ch);
    float a = b2f(lo[e]), b = b2f(hi[e]);
    nlo[e] = f2b(a * cl - b * sl);
    nhi[e] = f2b(b * ch + a * sh);
  }
  *(u16x8*)base = nlo;
  *(u16x8*)(base + 32) = nhi;
}

// ---------------- kernel 3: flash attention ----------------
// 8 waves x 16 q-rows (QBLK=128), KV tile 64. Swapped QK^T: S^T = mfma(K, Q)
// so col = q is lane-local for softmax (2 shfl_xor column reduce).
__global__ __launch_bounds__(512) void k_attn(const u16* __restrict__ qw,
                                              const u16* __restrict__ kw,
                                              const u16* __restrict__ vw,
                                              u16* __restrict__ ow) {
  __shared__ char lds[65536];  // K tile [64][256] @0 ; V^T tile [256][64] @32768
  const int tid = threadIdx.x;
  const int h = blockIdx.x & 31, qb = blockIdx.x >> 5;  // head->XCD affinity
  const int wid = tid >> 6, lane = tid & 63, lq = lane & 15, g = lane >> 4;
  const int q0 = qb * 128 + wid * 16;
  const float SM = 0.08838834764831845f * 1.4426950408889634f;  // SCALE*log2e

  const u16* qrow = qw + ((size_t)h * 2048 + q0 + lq) * 256;
  u16x8 qf[8];
#pragma unroll
  for (int ds = 0; ds < 8; ++ds) qf[ds] = *(const u16x8*)(qrow + ds * 32 + g * 8);

  f32x4 oacc[16] = {};
  float mrun = -1e30f, lrun = 0.f;
  const u16* kbase = kw + (size_t)h * 2048 * 256;
  const u16* vbase = vw + (size_t)h * 256 * 2048;

  for (int t = 0; t < 32; ++t) {
    const int kv0 = t * 64;
#pragma unroll
    for (int p = 0; p < 4; ++p) {
      int kr = p * 16 + (tid >> 5);
      int d0 = (tid & 31) * 8;
      *(u16x8*)(lds + swz(kr, d0, 512)) =
          *(const u16x8*)(kbase + (size_t)(kv0 + kr) * 256 + d0);
      int dr = p * 64 + (tid >> 3);
      int kc = (tid & 7) * 8;
      *(u16x8*)(lds + 32768 + swz(dr, kc, 128)) =
          *(const u16x8*)(vbase + (size_t)dr * 2048 + kv0 + kc);
    }
    __syncthreads();

    // S^T = K * Q^T : row = kv, col = q
    f32x4 sa[4] = {};
#pragma unroll
    for (int ds = 0; ds < 8; ++ds) {
#pragma unroll
      for (int f = 0; f < 4; ++f) {
        int kr = f * 16 + lq;
        u16x8 ka = *(const u16x8*)(lds + swz(kr, ds * 32 + g * 8, 512));
        sa[f] = mfma16(ka, qf[ds], sa[f]);
      }
    }
    // online softmax in log2 domain
    float ps[4][4];
    float mt = -1e30f;
#pragma unroll
    for (int f = 0; f < 4; ++f)
#pragma unroll
      for (int r = 0; r < 4; ++r) {
        ps[f][r] = sa[f][r] * SM;
        mt = fmaxf(mt, ps[f][r]);
      }
    mt = fmaxf(mt, __shfl_xor(mt, 16));
    mt = fmaxf(mt, __shfl_xor(mt, 32));
    float mnew = fmaxf(mrun, mt);
    float corr = exp2f(mrun - mnew);
    float lt = 0.f;
    u32 pk[4][2];
#pragma unroll
    for (int f = 0; f < 4; ++f) {
      float p0 = exp2f(ps[f][0] - mnew);
      float p1 = exp2f(ps[f][1] - mnew);
      float p2 = exp2f(ps[f][2] - mnew);
      float p3 = exp2f(ps[f][3] - mnew);
      lt += (p0 + p1) + (p2 + p3);
      pk[f][0] = pack2(p0, p1);
      pk[f][1] = pack2(p2, p3);
    }
    lt += __shfl_xor(lt, 16);
    lt += __shfl_xor(lt, 32);
    lrun = lrun * corr + lt;
    mrun = mnew;
#pragma unroll
    for (int di = 0; di < 16; ++di) {
      oacc[di][0] *= corr; oacc[di][1] *= corr;
      oacc[di][2] *= corr; oacc[di][3] *= corr;
    }
    // PV: O^T = V^T * P^T. Build P B-frag via shuffles (shared by all d-frags).
#pragma unroll
    for (int s = 0; s < 2; ++s) {
      u32 bu[4];
#pragma unroll
      for (int tt = 0; tt < 4; ++tt) {
        int src = (2 * (g & 1) + (tt >> 1)) * 16 + lq;
        u32 vlo = (u32)__shfl((int)pk[2 * s][tt & 1], src);
        u32 vhi = (u32)__shfl((int)pk[2 * s + 1][tt & 1], src);
        bu[tt] = (g < 2) ? vlo : vhi;
      }
      u16x8 pb;
#pragma unroll
      for (int tt = 0; tt < 4; ++tt) {
        pb[2 * tt] = (u16)(bu[tt] & 0xffff);
        pb[2 * tt + 1] = (u16)(bu[tt] >> 16);
      }
#pragma unroll
      for (int di = 0; di < 16; ++di) {
        int dr = di * 16 + lq;
        u16x8 va = *(const u16x8*)(lds + 32768 + swz(dr, s * 32 + g * 8, 128));
        oacc[di] = mfma16(va, pb, oacc[di]);
      }
    }
    __syncthreads();
  }
  float inv = 1.0f / lrun;
  u16* orow = ow + (size_t)(q0 + lq) * 8192 + h * 256;
#pragma unroll
  for (int di = 0; di < 16; ++di) {
    u32x2 o2;
    o2.x = pack2(oacc[di][0] * inv, oacc[di][1] * inv);
    o2.y = pack2(oacc[di][2] * inv, oacc[di][3] * inv);
    *(u32x2*)(orow + di * 16 + g * 4) = o2;
  }
}

// ---------------- kernel 4: out-proj (split-K=8, fp32 partials) ------------
__global__ __launch_bounds__(256) void k_proj(const u16* __restrict__ ow,
                                              const u16* __restrict__ wp,
                                              float* __restrict__ part) {
  __shared__ char lds[49152];  // O tile [64][128] @0, Wp tile [128][128] @16384
  const int tid = threadIdx.x;
  const int nt = blockIdx.x >> 3, kc = blockIdx.x & 7;
  const int n0 = nt * 64, kb = kc * 1024;
  const int wid = tid >> 6, lane = tid & 63, lq = lane & 15, g = lane >> 4;
  f32x4 acc[8] = {};
  for (int kt = 0; kt < 8; ++kt) {
    int kk = kb + kt * 128;
#pragma unroll
    for (int p = 0; p < 4; ++p) {
      int nr = p * 16 + (tid >> 4);
      int k0 = (tid & 15) * 8;
      *(u16x8*)(lds + swz(nr, k0, 256)) =
          *(const u16x8*)(ow + (size_t)(n0 + nr) * 8192 + kk + k0);
    }
#pragma unroll
    for (int p = 0; p < 8; ++p) {
      int er = p * 16 + (tid >> 4);
      int k0 = (tid & 15) * 8;
      *(u16x8*)(lds + 16384 + swz(er, k0, 256)) =
          *(const u16x8*)(wp + (size_t)er * 8192 + kk + k0);
    }
    __syncthreads();
#pragma unroll
    for (int ks = 0; ks < 4; ++ks) {
      int nr = wid * 16 + lq;
      u16x8 oa = *(const u16x8*)(lds + swz(nr, ks * 32 + g * 8, 256));
#pragma unroll
      for (int ef = 0; ef < 8; ++ef) {
        int er = ef * 16 + lq;
        u16x8 wf = *(const u16x8*)(lds + 16384 + swz(er, ks * 32 + g * 8, 256));
        acc[ef] = mfma16(oa, wf, acc[ef]);
      }
    }
    __syncthreads();
  }
  float* pb = part + (size_t)kc * 262144;
#pragma unroll
  for (int ef = 0; ef < 8; ++ef)
#pragma unroll
    for (int r = 0; r < 4; ++r) {
      int n = n0 + wid * 16 + g * 4 + r;
      pb[n * 128 + ef * 16 + lq] = acc[ef][r];
    }
}

// ---------------- kernel 5: reduce partials + bias ----------------
__global__ __launch_bounds__(256) void k_reduce(const float* __restrict__ part,
                                                const float* __restrict__ bias,
                                                float* __restrict__ out) {
  int i = blockIdx.x * 256 + threadIdx.x;  // 262144 total, grid exact
  float s = bias[i & 127];
#pragma unroll
  for (int c = 0; c < 8; ++c) s += part[(size_t)c * 262144 + i];
  out[i] = s;
}

extern "C" void kernel_launch(void* const* d_in, const int* in_sizes, int n_in,
                              void* d_out, int out_size, void* d_ws, size_t ws_size,
                              hipStream_t stream) {
  const float* x = (const float*)d_in[0];
  const float* wqkv = (const float*)d_in[1];
  const float* wproj = (const float*)d_in[2];
  const float* bproj = (const float*)d_in[3];
  const float* rope = (const float*)d_in[4];
  char* ws = (char*)d_ws;
  // ws layout (bytes): total peak ~136.5 MiB
  u16* xb    = (u16*)(ws);                    // 512 KiB
  u16* wqkvb = (u16*)(ws + 524288);           // 6 MiB
  u16* wpb   = (u16*)(ws + 6815744);          // 2 MiB
  u16* qw    = (u16*)(ws + 8912896);          // 32 MiB [h][n][256]
  u16* kw    = (u16*)(ws + 42467328);         // 32 MiB [h][n][256]
  u16* vw    = (u16*)(ws + 76021760);         // 32 MiB [h][d][n] (V^T)
  u16* owv   = (u16*)(ws + 109576192);        // 32 MiB [n][8192]
  float* part = (float*)(ws + 8912896);       // 8 MiB, overlays dead qw

  k_cvt<<<128, 256, 0, stream>>>(x, xb, 32768);
  k_cvt<<<1536, 256, 0, stream>>>(wqkv, wqkvb, 393216);
  k_cvt<<<512, 256, 0, stream>>>(wproj, wpb, 131072);
  k_qkv<<<3072, 256, 0, stream>>>(xb, wqkvb, qw, kw, vw);
  k_rope<<<2048, 256, 0, stream>>>(qw, kw, rope);
  k_attn<<<512, 512, 0, stream>>>(qw, kw, vw, owv);
  k_proj<<<256, 256, 0, stream>>>(owv, wpb, part);
  k_reduce<<<1024, 256, 0, stream>>>(part, bproj, (float*)d_out);
}

// Round 2
// 269.825 us; speedup vs baseline: 1.6948x; 1.6948x over previous
//
#include <hip/hip_runtime.h>

// Fused attention block: x@Wqkv^T -> rotary -> flash attn -> @Wproj^T + b
// B=1 N=2048 DIM=128 HEADS=32 D=256 ROT=64, fp32 in/out, bf16 MFMA internals.

typedef unsigned short u16;
typedef unsigned int u32;
typedef __attribute__((ext_vector_type(8))) u16 u16x8;
typedef __attribute__((ext_vector_type(8))) __bf16 bf16x8;
typedef __attribute__((ext_vector_type(4))) float f32x4;
typedef __attribute__((ext_vector_type(2))) u32 u32x2;

#define DEV static __device__ __forceinline__

DEV u16 f2b(float f) {                 // fp32 -> bf16 RNE
  u32 u = __builtin_bit_cast(u32, f);
  u += 0x7fffu + ((u >> 16) & 1u);
  return (u16)(u >> 16);
}
DEV float b2f(u16 b) {
  u32 u = ((u32)b) << 16;
  return __builtin_bit_cast(float, u);
}
DEV u32 pack2(float a, float b) { return (u32)f2b(a) | ((u32)f2b(b) << 16); }

DEV f32x4 mfma16(u16x8 a, u16x8 b, f32x4 c) {
  return __builtin_amdgcn_mfma_f32_16x16x32_bf16(
      __builtin_bit_cast(bf16x8, a), __builtin_bit_cast(bf16x8, b), c, 0, 0, 0);
}

// XOR swizzle (G4/T2): byte offset within a tile whose rows are rowBytes wide.
// Valid only for rowBytes >= 128.
DEV int swz(int row, int kelem, int rowBytes) {
  return row * rowBytes + ((kelem * 2) ^ ((row & 7) << 4));
}

// global -> LDS DMA, 16B per lane. LDS dest = (wave-uniform) l + lane*16.
DEV void dma16(const void* g, void* l) {
  __builtin_amdgcn_global_load_lds(
      (const __attribute__((address_space(1))) void*)g,
      (__attribute__((address_space(3))) void*)l, 16, 0, 0);
}

// ---------------- kernel 0: fp32 -> bf16 convert ----------------
__global__ __launch_bounds__(256) void k_cvt(const float* __restrict__ src,
                                             u16* __restrict__ dst, int n8) {
  int i = blockIdx.x * 256 + threadIdx.x;
  if (i >= n8) return;
  const float4* s = (const float4*)src;
  float4 a = s[i * 2], b = s[i * 2 + 1];
  u16x8 o;
  o[0] = f2b(a.x); o[1] = f2b(a.y); o[2] = f2b(a.z); o[3] = f2b(a.w);
  o[4] = f2b(b.x); o[5] = f2b(b.y); o[6] = f2b(b.z); o[7] = f2b(b.w);
  *(u16x8*)(dst + (size_t)i * 8) = o;
}

// ---------------- kernel 1: QKV GEMM (M=2048,N=24576,K=128) ----------------
// Q,K written [h][n][256]; V written transposed [h][d][n].
__global__ __launch_bounds__(256) void k_qkv(const u16* __restrict__ xb,
                                             const u16* __restrict__ wb,
                                             u16* __restrict__ qw,
                                             u16* __restrict__ kw,
                                             u16* __restrict__ vw) {
  __shared__ char lds[65536];  // W tile [128][128] @0, x tile [128][128] @32768
  const int tid = threadIdx.x;
  const int rt = blockIdx.x % 192, nt = blockIdx.x / 192;
  const int r0 = rt * 128, n0 = nt * 128;
#pragma unroll
  for (int p = 0; p < 8; ++p) {
    int row = p * 16 + (tid >> 4);
    int k0 = (tid & 15) * 8;
    *(u16x8*)(lds + swz(row, k0, 256)) =
        *(const u16x8*)(wb + (size_t)(r0 + row) * 128 + k0);
    *(u16x8*)(lds + 32768 + swz(row, k0, 256)) =
        *(const u16x8*)(xb + (size_t)(n0 + row) * 128 + k0);
  }
  __syncthreads();
  const int wid = tid >> 6, lane = tid & 63, lq = lane & 15, g = lane >> 4;
  const int wr = wid >> 1, wn = wid & 1;
  const bool isV = (r0 >= 16384);
  f32x4 acc[4][4] = {};
#pragma unroll
  for (int ks = 0; ks < 4; ++ks) {
    u16x8 wa[4], xa[4];
#pragma unroll
    for (int i = 0; i < 4; ++i) {
      int rw = wr * 64 + i * 16 + lq;
      wa[i] = *(const u16x8*)(lds + swz(rw, ks * 32 + g * 8, 256));
      int rx = wn * 64 + i * 16 + lq;
      xa[i] = *(const u16x8*)(lds + 32768 + swz(rx, ks * 32 + g * 8, 256));
    }
    if (!isV) {
#pragma unroll
      for (int i = 0; i < 4; ++i)
#pragma unroll
        for (int j = 0; j < 4; ++j) acc[i][j] = mfma16(wa[i], xa[j], acc[i][j]);
    } else {
#pragma unroll
      for (int i = 0; i < 4; ++i)
#pragma unroll
        for (int j = 0; j < 4; ++j) acc[i][j] = mfma16(xa[j], wa[i], acc[i][j]);
    }
  }
  if (!isV) {
#pragma unroll
    for (int i = 0; i < 4; ++i) {
      int rb = r0 + wr * 64 + i * 16 + g * 4;
      u16* dst0 = (rb >= 8192) ? kw : qw;
      int hd = rb & 8191;
      int h = hd >> 8, db = hd & 255;
#pragma unroll
      for (int j = 0; j < 4; ++j) {
        int n = n0 + wn * 64 + j * 16 + lq;
        u32x2 pk;
        pk.x = pack2(acc[i][j][0], acc[i][j][1]);
        pk.y = pack2(acc[i][j][2], acc[i][j][3]);
        *(u32x2*)(dst0 + ((size_t)h * 2048 + n) * 256 + db) = pk;
      }
    }
  } else {
#pragma unroll
    for (int i = 0; i < 4; ++i) {
      int rc = r0 - 16384 + wr * 64 + i * 16 + lq;
      int h = rc >> 8, d = rc & 255;
#pragma unroll
      for (int j = 0; j < 4; ++j) {
        int nb = n0 + wn * 64 + j * 16 + g * 4;
        u32x2 pk;
        pk.x = pack2(acc[i][j][0], acc[i][j][1]);
        pk.y = pack2(acc[i][j][2], acc[i][j][3]);
        *(u32x2*)(vw + ((size_t)h * 256 + d) * 2048 + nb) = pk;
      }
    }
  }
}

// ---------------- kernel 2: rotary (in-place on Q,K, first 64 dims) --------
__global__ __launch_bounds__(256) void k_rope(u16* __restrict__ qw,
                                              u16* __restrict__ kw,
                                              const float* __restrict__ fr) {
  int idx = blockIdx.x * 256 + threadIdx.x;  // 2*32*2048*4 = 524288
  int seg = idx & 3;
  int n = (idx >> 2) & 2047;
  int h = (idx >> 13) & 31;
  u16* base = ((idx >> 18) ? kw : qw) + ((size_t)h * 2048 + n) * 256 + seg * 8;
  u16x8 lo = *(const u16x8*)base;
  u16x8 hi = *(const u16x8*)(base + 32);
  const float* f = fr + n * 64 + seg * 8;
  u16x8 nlo, nhi;
#pragma unroll
  for (int e = 0; e < 8; ++e) {
    float fl = f[e], fh = f[e + 32];
    float sl, cl, sh, ch;
    sincosf(fl, &sl, &cl);
    sincosf(fh, &sh, &ch);
    float a = b2f(lo[e]), b = b2f(hi[e]);
    nlo[e] = f2b(a * cl - b * sl);
    nhi[e] = f2b(b * ch + a * sh);
  }
  *(u16x8*)base = nlo;
  *(u16x8*)(base + 32) = nhi;
}

// ---------------- kernel 3: flash attention ----------------
// QBLK=256 (8 waves x 32 q-rows), KVBLK=32, double-buffered LDS staged by
// global_load_lds with pre-swizzled global source. Counted vmcnt(4) pipeline.
// Swapped QK^T: S^T = mfma(K, Q) so col = q is lane-local for softmax.
__global__ __launch_bounds__(512, 2) void k_attn(const u16* __restrict__ qw,
                                                 const u16* __restrict__ kw,
                                                 const u16* __restrict__ vw,
                                                 u16* __restrict__ ow) {
  // per buf (32KB): K [32 rows][512B] @0 ; V^T paired [128 L-rows][128B] @16384
  __shared__ char lds[65536];
  const int tid = threadIdx.x;
  const int j = blockIdx.x & 31;
  const int h = (j & 7) * 4 + (j >> 3);  // same head -> same XCD
  const int qb = blockIdx.x >> 5;
  const int wid = tid >> 6, lane = tid & 63, lq = lane & 15, g = lane >> 4;
  const int q0 = qb * 256 + wid * 32;
  const float SM = 0.08838834764831845f * 1.4426950408889634f;  // SCALE*log2e

  const u16* kbase = kw + (size_t)h * 2048 * 256;
  const u16* vbase = vw + (size_t)h * 256 * 2048;

  // ---- per-lane DMA source offsets (element units) ----
  // K: instr i covers rows wid*4+2i + (lane>>5); 32 slots of 8 elems.
  int kro[2], kgo[2];
#pragma unroll
  for (int i = 0; i < 2; ++i) {
    int r = wid * 4 + 2 * i + (lane >> 5);
    kro[i] = r;
    kgo[i] = r * 256 + (((lane & 31) ^ (r & 7)) * 8);
  }
  // V: instr i covers L-rows wid*16+8i + (lane>>3); 8 slots/L-row.
  // L-row L holds d = 2L + h2 at half h2, 4 kv-slots of 8 per half.
  int vgo[2];
#pragma unroll
  for (int i = 0; i < 2; ++i) {
    int L = wid * 16 + 8 * i + (lane >> 3);
    int l = (lane & 7) ^ (L & 7);
    int d = 2 * L + (l >> 2);
    vgo[i] = d * 2048 + (l & 3) * 8;
  }

  // ---- Q fragments: 32 q-rows (2 frags of 16) in registers ----
  u16x8 qf[2][8];
  {
    const u16* q0p = qw + ((size_t)h * 2048 + q0 + lq) * 256;
#pragma unroll
    for (int ds = 0; ds < 8; ++ds) {
      qf[0][ds] = *(const u16x8*)(q0p + ds * 32 + g * 8);
      qf[1][ds] = *(const u16x8*)(q0p + 16 * 256 + ds * 32 + g * 8);
    }
  }

  f32x4 oacc[2][16] = {};
  float mrun[2] = {-1e30f, -1e30f}, lrun[2] = {0.f, 0.f};

#define STAGE(T)                                                         \
  {                                                                      \
    const int kv0 = (T) * 32;                                            \
    char* kb = lds + ((T) & 1) * 32768;                                  \
    char* vb = kb + 16384;                                               \
    dma16(kbase + (size_t)kv0 * 256 + kgo[0], kb + (wid * 4) * 512);     \
    dma16(kbase + (size_t)kv0 * 256 + kgo[1], kb + (wid * 4 + 2) * 512); \
    dma16(vbase + (size_t)kv0 + vgo[0], vb + (wid * 16) * 128);          \
    dma16(vbase + (size_t)kv0 + vgo[1], vb + (wid * 16 + 8) * 128);     \
  }

  STAGE(0);

  for (int t = 0; t < 64; ++t) {
    if (t < 63) {
      STAGE(t + 1);
      asm volatile("s_waitcnt vmcnt(4)" ::: "memory");
    } else {
      asm volatile("s_waitcnt vmcnt(0)" ::: "memory");
    }
    __builtin_amdgcn_s_barrier();
    asm volatile("" ::: "memory");

    const char* kb = lds + (t & 1) * 32768;
    const char* vb = kb + 16384;

    // ---- S^T = K * Q^T ----
    f32x4 sa[2][2] = {};
    __builtin_amdgcn_s_setprio(1);
#pragma unroll
    for (int ds = 0; ds < 8; ++ds) {
#pragma unroll
      for (int f = 0; f < 2; ++f) {
        int kr = f * 16 + lq;
        u16x8 ka = *(const u16x8*)(kb + kr * 512 +
                                   ((((ds << 2) | g) ^ (kr & 7)) << 4));
        sa[0][f] = mfma16(ka, qf[0][ds], sa[0][f]);
        sa[1][f] = mfma16(ka, qf[1][ds], sa[1][f]);
      }
    }
    __builtin_amdgcn_s_setprio(0);

    // ---- online softmax (log2 domain), defer-max threshold 8 ----
    u32 pk[2][2][2];
#pragma unroll
    for (int c = 0; c < 2; ++c) {
      float ps[2][4];
      float mt = -1e30f;
#pragma unroll
      for (int f = 0; f < 2; ++f)
#pragma unroll
        for (int r = 0; r < 4; ++r) {
          ps[f][r] = sa[c][f][r] * SM;
          mt = fmaxf(mt, ps[f][r]);
        }
      mt = fmaxf(mt, __shfl_xor(mt, 16));
      mt = fmaxf(mt, __shfl_xor(mt, 32));
      bool skip = __all(mt - mrun[c] <= 8.0f);
      if (!skip) {
        float mnew = fmaxf(mrun[c], mt);
        float corr = exp2f(mrun[c] - mnew);
        lrun[c] *= corr;
#pragma unroll
        for (int di = 0; di < 16; ++di) {
          oacc[c][di][0] *= corr; oacc[c][di][1] *= corr;
          oacc[c][di][2] *= corr; oacc[c][di][3] *= corr;
        }
        mrun[c] = mnew;
      }
      float lt = 0.f;
#pragma unroll
      for (int f = 0; f < 2; ++f) {
        float p0 = exp2f(ps[f][0] - mrun[c]);
        float p1 = exp2f(ps[f][1] - mrun[c]);
        float p2 = exp2f(ps[f][2] - mrun[c]);
        float p3 = exp2f(ps[f][3] - mrun[c]);
        lt += (p0 + p1) + (p2 + p3);
        pk[c][f][0] = pack2(p0, p1);
        pk[c][f][1] = pack2(p2, p3);
      }
      lt += __shfl_xor(lt, 16);
      lt += __shfl_xor(lt, 32);
      lrun[c] += lt;
    }

    // ---- build P B-frags (kv 0..31 chunk) via shuffles ----
    u16x8 pb[2];
#pragma unroll
    for (int c = 0; c < 2; ++c) {
      u32 bu[4];
#pragma unroll
      for (int tt = 0; tt < 4; ++tt) {
        int src = (2 * (g & 1) + (tt >> 1)) * 16 + lq;
        u32 vlo = (u32)__shfl((int)pk[c][0][tt & 1], src);
        u32 vhi = (u32)__shfl((int)pk[c][1][tt & 1], src);
        bu[tt] = (g < 2) ? vlo : vhi;
      }
#pragma unroll
      for (int tt = 0; tt < 4; ++tt) {
        pb[c][2 * tt] = (u16)(bu[tt] & 0xffff);
        pb[c][2 * tt + 1] = (u16)(bu[tt] >> 16);
      }
    }

    // ---- PV: O^T += V^T * P^T ----
    __builtin_amdgcn_s_setprio(1);
#pragma unroll
    for (int di = 0; di < 16; ++di) {
      int dr = di * 16 + lq;
      int L = dr >> 1;
      u16x8 va = *(const u16x8*)(
          vb + L * 128 + ((((((dr & 1) << 2) | g) ^ (L & 7))) << 4));
      oacc[0][di] = mfma16(va, pb[0], oacc[0][di]);
      oacc[1][di] = mfma16(va, pb[1], oacc[1][di]);
    }
    __builtin_amdgcn_s_setprio(0);

    __builtin_amdgcn_s_barrier();
    asm volatile("" ::: "memory");
  }
#undef STAGE

#pragma unroll
  for (int c = 0; c < 2; ++c) {
    float inv = 1.0f / lrun[c];
    u16* orow = ow + (size_t)(q0 + c * 16 + lq) * 8192 + h * 256;
#pragma unroll
    for (int di = 0; di < 16; ++di) {
      u32x2 o2;
      o2.x = pack2(oacc[c][di][0] * inv, oacc[c][di][1] * inv);
      o2.y = pack2(oacc[c][di][2] * inv, oacc[c][di][3] * inv);
      *(u32x2*)(orow + di * 16 + g * 4) = o2;
    }
  }
}

// ---------------- kernel 4: out-proj (split-K=8, fp32 partials) ------------
__global__ __launch_bounds__(256) void k_proj(const u16* __restrict__ ow,
                                              const u16* __restrict__ wp,
                                              float* __restrict__ part) {
  __shared__ char lds[49152];  // O tile [64][128] @0, Wp tile [128][128] @16384
  const int tid = threadIdx.x;
  const int nt = blockIdx.x >> 3, kc = blockIdx.x & 7;
  const int n0 = nt * 64, kb = kc * 1024;
  const int wid = tid >> 6, lane = tid & 63, lq = lane & 15, g = lane >> 4;
  f32x4 acc[8] = {};
  for (int kt = 0; kt < 8; ++kt) {
    int kk = kb + kt * 128;
#pragma unroll
    for (int p = 0; p < 4; ++p) {
      int nr = p * 16 + (tid >> 4);
      int k0 = (tid & 15) * 8;
      *(u16x8*)(lds + swz(nr, k0, 256)) =
          *(const u16x8*)(ow + (size_t)(n0 + nr) * 8192 + kk + k0);
    }
#pragma unroll
    for (int p = 0; p < 8; ++p) {
      int er = p * 16 + (tid >> 4);
      int k0 = (tid & 15) * 8;
      *(u16x8*)(lds + 16384 + swz(er, k0, 256)) =
          *(const u16x8*)(wp + (size_t)er * 8192 + kk + k0);
    }
    __syncthreads();
#pragma unroll
    for (int ks = 0; ks < 4; ++ks) {
      int nr = wid * 16 + lq;
      u16x8 oa = *(const u16x8*)(lds + swz(nr, ks * 32 + g * 8, 256));
#pragma unroll
      for (int ef = 0; ef < 8; ++ef) {
        int er = ef * 16 + lq;
        u16x8 wf = *(const u16x8*)(lds + 16384 + swz(er, ks * 32 + g * 8, 256));
        acc[ef] = mfma16(oa, wf, acc[ef]);
      }
    }
    __syncthreads();
  }
  float* pb = part + (size_t)kc * 262144;
#pragma unroll
  for (int ef = 0; ef < 8; ++ef)
#pragma unroll
    for (int r = 0; r < 4; ++r) {
      int n = n0 + wid * 16 + g * 4 + r;
      pb[n * 128 + ef * 16 + lq] = acc[ef][r];
    }
}

// ---------------- kernel 5: reduce partials + bias ----------------
__global__ __launch_bounds__(256) void k_reduce(const float* __restrict__ part,
                                                const float* __restrict__ bias,
                                                float* __restrict__ out) {
  int i = blockIdx.x * 256 + threadIdx.x;  // 262144 total, grid exact
  float s = bias[i & 127];
#pragma unroll
  for (int c = 0; c < 8; ++c) s += part[(size_t)c * 262144 + i];
  out[i] = s;
}

extern "C" void kernel_launch(void* const* d_in, const int* in_sizes, int n_in,
                              void* d_out, int out_size, void* d_ws, size_t ws_size,
                              hipStream_t stream) {
  const float* x = (const float*)d_in[0];
  const float* wqkv = (const float*)d_in[1];
  const float* wproj = (const float*)d_in[2];
  const float* bproj = (const float*)d_in[3];
  const float* rope = (const float*)d_in[4];
  char* ws = (char*)d_ws;
  u16* xb    = (u16*)(ws);                    // 512 KiB
  u16* wqkvb = (u16*)(ws + 524288);           // 6 MiB
  u16* wpb   = (u16*)(ws + 6815744);          // 2 MiB
  u16* qw    = (u16*)(ws + 8912896);          // 32 MiB [h][n][256]
  u16* kw    = (u16*)(ws + 42467328);         // 32 MiB [h][n][256]
  u16* vw    = (u16*)(ws + 76021760);         // 32 MiB [h][d][n] (V^T)
  u16* owv   = (u16*)(ws + 109576192);        // 32 MiB [n][8192]
  float* part = (float*)(ws + 8912896);       // 8 MiB, overlays dead qw

  k_cvt<<<128, 256, 0, stream>>>(x, xb, 32768);
  k_cvt<<<1536, 256, 0, stream>>>(wqkv, wqkvb, 393216);
  k_cvt<<<512, 256, 0, stream>>>(wproj, wpb, 131072);
  k_qkv<<<3072, 256, 0, stream>>>(xb, wqkvb, qw, kw, vw);
  k_rope<<<2048, 256, 0, stream>>>(qw, kw, rope);
  k_attn<<<256, 512, 0, stream>>>(qw, kw, vw, owv);
  k_proj<<<256, 256, 0, stream>>>(owv, wpb, part);
  k_reduce<<<1024, 256, 0, stream>>>(part, bproj, (float*)d_out);
}

// Round 3
// 265.795 us; speedup vs baseline: 1.7204x; 1.0152x over previous
//
#include <hip/hip_runtime.h>

// Fused attention block: x@Wqkv^T -> rotary -> flash attn -> @Wproj^T + b
// B=1 N=2048 DIM=128 HEADS=32 D=256 ROT=64, fp32 in/out, bf16 MFMA internals.

typedef unsigned short u16;
typedef unsigned int u32;
typedef __attribute__((ext_vector_type(8))) u16 u16x8;
typedef __attribute__((ext_vector_type(8))) __bf16 bf16x8;
typedef __attribute__((ext_vector_type(4))) float f32x4;
typedef __attribute__((ext_vector_type(4))) u32 u32x4;
typedef __attribute__((ext_vector_type(2))) u32 u32x2;

#define DEV static __device__ __forceinline__

DEV u16 f2b(float f) {                 // native RNE convert (v_cvt_pk-able)
  __bf16 h = (__bf16)f;
  return __builtin_bit_cast(u16, h);
}
DEV float b2f(u16 b) {
  u32 u = ((u32)b) << 16;
  return __builtin_bit_cast(float, u);
}
DEV u32 pk2(float a, float b) { return (u32)f2b(a) | ((u32)f2b(b) << 16); }

DEV f32x4 mfma16(u16x8 a, u16x8 b, f32x4 c) {
  return __builtin_amdgcn_mfma_f32_16x16x32_bf16(
      __builtin_bit_cast(bf16x8, a), __builtin_bit_cast(bf16x8, b), c, 0, 0, 0);
}

// XOR swizzle for the GEMM kernels (rowBytes >= 128).
DEV int swz(int row, int kelem, int rowBytes) {
  return row * rowBytes + ((kelem * 2) ^ ((row & 7) << 4));
}

// global -> LDS DMA, 16B per lane. LDS dest = (wave-uniform) l + lane*16.
DEV void dma16(const void* g, void* l) {
  __builtin_amdgcn_global_load_lds(
      (const __attribute__((address_space(1))) void*)g,
      (__attribute__((address_space(3))) void*)l, 16, 0, 0);
}

// ---------------- kernel 0: fp32 -> bf16 convert ----------------
__global__ __launch_bounds__(256) void k_cvt(const float* __restrict__ src,
                                             u16* __restrict__ dst, int n8) {
  int i = blockIdx.x * 256 + threadIdx.x;
  if (i >= n8) return;
  const float4* s = (const float4*)src;
  float4 a = s[i * 2], b = s[i * 2 + 1];
  u16x8 o;
  o[0] = f2b(a.x); o[1] = f2b(a.y); o[2] = f2b(a.z); o[3] = f2b(a.w);
  o[4] = f2b(b.x); o[5] = f2b(b.y); o[6] = f2b(b.z); o[7] = f2b(b.w);
  *(u16x8*)(dst + (size_t)i * 8) = o;
}

// ---------------- kernel 1: QKV GEMM (M=2048,N=24576,K=128) ----------------
// Q,K written [h][n][256] (Q pre-scaled by SCALE*log2e); V^T written [h][d][n].
__global__ __launch_bounds__(256) void k_qkv(const u16* __restrict__ xb,
                                             const u16* __restrict__ wb,
                                             u16* __restrict__ qw,
                                             u16* __restrict__ kw,
                                             u16* __restrict__ vw) {
  __shared__ char lds[65536];  // W tile [128][128] @0, x tile [128][128] @32768
  const int tid = threadIdx.x;
  const int rt = blockIdx.x % 192, nt = blockIdx.x / 192;
  const int r0 = rt * 128, n0 = nt * 128;
#pragma unroll
  for (int p = 0; p < 8; ++p) {
    int row = p * 16 + (tid >> 4);
    int k0 = (tid & 15) * 8;
    *(u16x8*)(lds + swz(row, k0, 256)) =
        *(const u16x8*)(wb + (size_t)(r0 + row) * 128 + k0);
    *(u16x8*)(lds + 32768 + swz(row, k0, 256)) =
        *(const u16x8*)(xb + (size_t)(n0 + row) * 128 + k0);
  }
  __syncthreads();
  const int wid = tid >> 6, lane = tid & 63, lq = lane & 15, g = lane >> 4;
  const int wr = wid >> 1, wn = wid & 1;
  const bool isV = (r0 >= 16384);
  f32x4 acc[4][4] = {};
#pragma unroll
  for (int ks = 0; ks < 4; ++ks) {
    u16x8 wa[4], xa[4];
#pragma unroll
    for (int i = 0; i < 4; ++i) {
      int rw = wr * 64 + i * 16 + lq;
      wa[i] = *(const u16x8*)(lds + swz(rw, ks * 32 + g * 8, 256));
      int rx = wn * 64 + i * 16 + lq;
      xa[i] = *(const u16x8*)(lds + 32768 + swz(rx, ks * 32 + g * 8, 256));
    }
    if (!isV) {
#pragma unroll
      for (int i = 0; i < 4; ++i)
#pragma unroll
        for (int j = 0; j < 4; ++j) acc[i][j] = mfma16(wa[i], xa[j], acc[i][j]);
    } else {
#pragma unroll
      for (int i = 0; i < 4; ++i)
#pragma unroll
        for (int j = 0; j < 4; ++j) acc[i][j] = mfma16(xa[j], wa[i], acc[i][j]);
    }
  }
  const float SMQ = 0.08838834764831845f * 1.4426950408889634f;
  if (!isV) {
#pragma unroll
    for (int i = 0; i < 4; ++i) {
      int rb = r0 + wr * 64 + i * 16 + g * 4;
      u16* dst0 = (rb >= 8192) ? kw : qw;
      float scl = (rb >= 8192) ? 1.0f : SMQ;   // fold softmax scale into Q
      int hd = rb & 8191;
      int h = hd >> 8, db = hd & 255;
#pragma unroll
      for (int j = 0; j < 4; ++j) {
        int n = n0 + wn * 64 + j * 16 + lq;
        u32x2 pk;
        pk.x = pk2(acc[i][j][0] * scl, acc[i][j][1] * scl);
        pk.y = pk2(acc[i][j][2] * scl, acc[i][j][3] * scl);
        *(u32x2*)(dst0 + ((size_t)h * 2048 + n) * 256 + db) = pk;
      }
    }
  } else {
#pragma unroll
    for (int i = 0; i < 4; ++i) {
      int rc = r0 - 16384 + wr * 64 + i * 16 + lq;
      int h = rc >> 8, d = rc & 255;
#pragma unroll
      for (int j = 0; j < 4; ++j) {
        int nb = n0 + wn * 64 + j * 16 + g * 4;
        u32x2 pk;
        pk.x = pk2(acc[i][j][0], acc[i][j][1]);
        pk.y = pk2(acc[i][j][2], acc[i][j][3]);
        *(u32x2*)(vw + ((size_t)h * 256 + d) * 2048 + nb) = pk;
      }
    }
  }
}

// ---------------- kernel 2: rotary (in-place on Q,K, first 64 dims) --------
__global__ __launch_bounds__(256) void k_rope(u16* __restrict__ qw,
                                              u16* __restrict__ kw,
                                              const float* __restrict__ fr) {
  int idx = blockIdx.x * 256 + threadIdx.x;  // 2*32*2048*4 = 524288
  int seg = idx & 3;
  int n = (idx >> 2) & 2047;
  int h = (idx >> 13) & 31;
  u16* base = ((idx >> 18) ? kw : qw) + ((size_t)h * 2048 + n) * 256 + seg * 8;
  u16x8 lo = *(const u16x8*)base;
  u16x8 hi = *(const u16x8*)(base + 32);
  const float* f = fr + n * 64 + seg * 8;
  u16x8 nlo, nhi;
#pragma unroll
  for (int e = 0; e < 8; ++e) {
    float fl = f[e], fh = f[e + 32];
    float sl, cl, sh, ch;
    __sincosf(fl, &sl, &cl);
    __sincosf(fh, &sh, &ch);
    float a = b2f(lo[e]), b = b2f(hi[e]);
    nlo[e] = f2b(a * cl - b * sl);
    nhi[e] = f2b(b * ch + a * sh);
  }
  *(u16x8*)base = nlo;
  *(u16x8*)(base + 32) = nhi;
}

// ---------------- kernel 3: flash attention ----------------
// QBLK=128 (4 waves x 32 q), KVBLK=32, 2 blocks/CU (two barrier domains).
// Double-buffered LDS via global_load_lds, counted vmcnt(8) pipeline.
// XOR-swizzle uses row&3 only -> ds offsets fold to immediates, <=2-way banks.
__global__ __launch_bounds__(256, 2) void k_attn(const u16* __restrict__ qw,
                                                 const u16* __restrict__ kw,
                                                 const u16* __restrict__ vw,
                                                 u16* __restrict__ ow) {
  // per buf (32KB): K [32 rows][512B] @0 ; V^T [128 L-rows][128B] @16384
  __shared__ char lds[65536];
  const int tid = threadIdx.x;
  const int j = blockIdx.x & 31;
  const int h = j;                       // head's 16 blocks share XCD (b&7=j&7)
  const int qb = blockIdx.x >> 5;
  const int wid = tid >> 6, lane = tid & 63, lq = lane & 15, g = lane >> 4;
  const int q0 = qb * 128 + wid * 32;

  const u16* kbase = kw + (size_t)h * 2048 * 256;
  const u16* vbase = vw + (size_t)h * 256 * 2048;

  // ---- per-lane DMA source offsets (element units) ----
  int kgo[4], vgo[4];
#pragma unroll
  for (int i = 0; i < 4; ++i) {
    int r = wid * 8 + 2 * i + (lane >> 5);            // K row
    kgo[i] = r * 256 + (((lane & 31) ^ (r & 3)) * 8);
    int L = wid * 32 + 8 * i + (lane >> 3);           // V L-row (d pair)
    int cs = (lane & 7) ^ (L & 3);
    int d = 2 * L + (cs >> 2);
    vgo[i] = d * 2048 + (cs & 3) * 8;
  }

  // ---- per-lane LDS read bases (byte units, within buffer) ----
  const int kread = lq * 512 + ((g ^ (lq & 3)) << 4);          // +f*8192+ds*64
  const int vread = 16384 + (lq >> 1) * 128 + ((lq & 1) << 6)  // +di*1024
                    + ((g ^ ((lq >> 1) & 3)) << 4);

  // ---- Q fragments: 32 q-rows (2 frags of 16) in registers ----
  u16x8 qf[2][8];
  {
    const u16* q0p = qw + ((size_t)h * 2048 + q0 + lq) * 256;
#pragma unroll
    for (int ds = 0; ds < 8; ++ds) {
      qf[0][ds] = *(const u16x8*)(q0p + ds * 32 + g * 8);
      qf[1][ds] = *(const u16x8*)(q0p + 16 * 256 + ds * 32 + g * 8);
    }
  }

  f32x4 oacc[2][16] = {};
  float mrun[2] = {-1e30f, -1e30f}, lrun[2] = {0.f, 0.f};

#define STAGE(T)                                                          \
  {                                                                       \
    const int kv0 = (T) * 32;                                             \
    char* kb_ = lds + ((T) & 1) * 32768;                                  \
    char* vb_ = kb_ + 16384;                                              \
    _Pragma("unroll") for (int i = 0; i < 4; ++i) {                       \
      dma16(kbase + (size_t)kv0 * 256 + kgo[i],                           \
            kb_ + (wid * 8 + 2 * i) * 512);                               \
      dma16(vbase + (size_t)kv0 + vgo[i], vb_ + (wid * 32 + 8 * i) * 128);\
    }                                                                     \
  }

  STAGE(0);

  for (int t = 0; t < 64; ++t) {
    if (t < 63) {
      STAGE(t + 1);
      asm volatile("s_waitcnt vmcnt(8)" ::: "memory");
    } else {
      asm volatile("s_waitcnt vmcnt(0)" ::: "memory");
    }
    __builtin_amdgcn_s_barrier();
    asm volatile("" ::: "memory");

    const char* kb = lds + (t & 1) * 32768;

    // ---- S^T = K * Q^T ----
    f32x4 sa[2][2] = {};
    __builtin_amdgcn_s_setprio(1);
#pragma unroll
    for (int ds = 0; ds < 8; ++ds) {
#pragma unroll
      for (int f = 0; f < 2; ++f) {
        u16x8 ka = *(const u16x8*)(kb + kread + f * 8192 + ds * 64);
        sa[0][f] = mfma16(ka, qf[0][ds], sa[0][f]);
        sa[1][f] = mfma16(ka, qf[1][ds], sa[1][f]);
      }
    }
    __builtin_amdgcn_s_setprio(0);

    // ---- online softmax (log2 domain, scale pre-folded), defer-max ----
    u32 pk[2][2][2];
#pragma unroll
    for (int c = 0; c < 2; ++c) {
      float mt = -1e30f;
#pragma unroll
      for (int f = 0; f < 2; ++f)
#pragma unroll
        for (int r = 0; r < 4; ++r) mt = fmaxf(mt, sa[c][f][r]);
      mt = fmaxf(mt, __shfl_xor(mt, 16));
      mt = fmaxf(mt, __shfl_xor(mt, 32));
      bool skip = __all(mt - mrun[c] <= 8.0f);
      if (!skip) {
        float mnew = fmaxf(mrun[c], mt);
        float corr = exp2f(mrun[c] - mnew);
        lrun[c] *= corr;
#pragma unroll
        for (int di = 0; di < 16; ++di) {
          oacc[c][di][0] *= corr; oacc[c][di][1] *= corr;
          oacc[c][di][2] *= corr; oacc[c][di][3] *= corr;
        }
        mrun[c] = mnew;
      }
      float lt = 0.f;
#pragma unroll
      for (int f = 0; f < 2; ++f) {
        float p0 = exp2f(sa[c][f][0] - mrun[c]);
        float p1 = exp2f(sa[c][f][1] - mrun[c]);
        float p2 = exp2f(sa[c][f][2] - mrun[c]);
        float p3 = exp2f(sa[c][f][3] - mrun[c]);
        lt += (p0 + p1) + (p2 + p3);
        pk[c][f][0] = pk2(p0, p1);
        pk[c][f][1] = pk2(p2, p3);
      }
      lt += __shfl_xor(lt, 16);
      lt += __shfl_xor(lt, 32);
      lrun[c] += lt;
    }

    // ---- build P B-frags via shuffles (u32 pairs -> bit_cast) ----
    u16x8 pb[2];
#pragma unroll
    for (int c = 0; c < 2; ++c) {
      u32x4 bu;
#pragma unroll
      for (int tt = 0; tt < 4; ++tt) {
        int src = (2 * (g & 1) + (tt >> 1)) * 16 + lq;
        u32 vlo = (u32)__shfl((int)pk[c][0][tt & 1], src);
        u32 vhi = (u32)__shfl((int)pk[c][1][tt & 1], src);
        bu[tt] = (g < 2) ? vlo : vhi;
      }
      pb[c] = __builtin_bit_cast(u16x8, bu);
    }

    // ---- PV: O^T += V^T * P^T ----
    __builtin_amdgcn_s_setprio(1);
#pragma unroll
    for (int di = 0; di < 16; ++di) {
      u16x8 va = *(const u16x8*)(kb + vread + di * 1024);
      oacc[0][di] = mfma16(va, pb[0], oacc[0][di]);
      oacc[1][di] = mfma16(va, pb[1], oacc[1][di]);
    }
    __builtin_amdgcn_s_setprio(0);

    __builtin_amdgcn_s_barrier();
    asm volatile("" ::: "memory");
  }
#undef STAGE

#pragma unroll
  for (int c = 0; c < 2; ++c) {
    float inv = 1.0f / lrun[c];
    u16* orow = ow + (size_t)(q0 + c * 16 + lq) * 8192 + h * 256;
#pragma unroll
    for (int di = 0; di < 16; ++di) {
      u32x2 o2;
      o2.x = pk2(oacc[c][di][0] * inv, oacc[c][di][1] * inv);
      o2.y = pk2(oacc[c][di][2] * inv, oacc[c][di][3] * inv);
      *(u32x2*)(orow + di * 16 + g * 4) = o2;
    }
  }
}

// ---------------- kernel 4: out-proj (split-K=8, fp32 partials) ------------
__global__ __launch_bounds__(256) void k_proj(const u16* __restrict__ ow,
                                              const u16* __restrict__ wp,
                                              float* __restrict__ part) {
  __shared__ char lds[49152];  // O tile [64][128] @0, Wp tile [128][128] @16384
  const int tid = threadIdx.x;
  const int nt = blockIdx.x >> 3, kc = blockIdx.x & 7;
  const int n0 = nt * 64, kb = kc * 1024;
  const int wid = tid >> 6, lane = tid & 63, lq = lane & 15, g = lane >> 4;
  f32x4 acc[8] = {};
  for (int kt = 0; kt < 8; ++kt) {
    int kk = kb + kt * 128;
#pragma unroll
    for (int p = 0; p < 4; ++p) {
      int nr = p * 16 + (tid >> 4);
      int k0 = (tid & 15) * 8;
      *(u16x8*)(lds + swz(nr, k0, 256)) =
          *(const u16x8*)(ow + (size_t)(n0 + nr) * 8192 + kk + k0);
    }
#pragma unroll
    for (int p = 0; p < 8; ++p) {
      int er = p * 16 + (tid >> 4);
      int k0 = (tid & 15) * 8;
      *(u16x8*)(lds + 16384 + swz(er, k0, 256)) =
          *(const u16x8*)(wp + (size_t)er * 8192 + kk + k0);
    }
    __syncthreads();
#pragma unroll
    for (int ks = 0; ks < 4; ++ks) {
      int nr = wid * 16 + lq;
      u16x8 oa = *(const u16x8*)(lds + swz(nr, ks * 32 + g * 8, 256));
#pragma unroll
      for (int ef = 0; ef < 8; ++ef) {
        int er = ef * 16 + lq;
        u16x8 wf = *(const u16x8*)(lds + 16384 + swz(er, ks * 32 + g * 8, 256));
        acc[ef] = mfma16(oa, wf, acc[ef]);
      }
    }
    __syncthreads();
  }
  float* pb = part + (size_t)kc * 262144;
#pragma unroll
  for (int ef = 0; ef < 8; ++ef)
#pragma unroll
    for (int r = 0; r < 4; ++r) {
      int n = n0 + wid * 16 + g * 4 + r;
      pb[n * 128 + ef * 16 + lq] = acc[ef][r];
    }
}

// ---------------- kernel 5: reduce partials + bias ----------------
__global__ __launch_bounds__(256) void k_reduce(const float* __restrict__ part,
                                                const float* __restrict__ bias,
                                                float* __restrict__ out) {
  int i = blockIdx.x * 256 + threadIdx.x;  // 262144 total, grid exact
  float s = bias[i & 127];
#pragma unroll
  for (int c = 0; c < 8; ++c) s += part[(size_t)c * 262144 + i];
  out[i] = s;
}

extern "C" void kernel_launch(void* const* d_in, const int* in_sizes, int n_in,
                              void* d_out, int out_size, void* d_ws, size_t ws_size,
                              hipStream_t stream) {
  const float* x = (const float*)d_in[0];
  const float* wqkv = (const float*)d_in[1];
  const float* wproj = (const float*)d_in[2];
  const float* bproj = (const float*)d_in[3];
  const float* rope = (const float*)d_in[4];
  char* ws = (char*)d_ws;
  u16* xb    = (u16*)(ws);                    // 512 KiB
  u16* wqkvb = (u16*)(ws + 524288);           // 6 MiB
  u16* wpb   = (u16*)(ws + 6815744);          // 2 MiB
  u16* qw    = (u16*)(ws + 8912896);          // 32 MiB [h][n][256]
  u16* kw    = (u16*)(ws + 42467328);         // 32 MiB [h][n][256]
  u16* vw    = (u16*)(ws + 76021760);         // 32 MiB [h][d][n] (V^T)
  u16* owv   = (u16*)(ws + 109576192);        // 32 MiB [n][8192]
  float* part = (float*)(ws + 8912896);       // 8 MiB, overlays dead qw

  k_cvt<<<128, 256, 0, stream>>>(x, xb, 32768);
  k_cvt<<<1536, 256, 0, stream>>>(wqkv, wqkvb, 393216);
  k_cvt<<<512, 256, 0, stream>>>(wproj, wpb, 131072);
  k_qkv<<<3072, 256, 0, stream>>>(xb, wqkvb, qw, kw, vw);
  k_rope<<<2048, 256, 0, stream>>>(qw, kw, rope);
  k_attn<<<512, 256, 0, stream>>>(qw, kw, vw, owv);
  k_proj<<<256, 256, 0, stream>>>(owv, wpb, part);
  k_reduce<<<1024, 256, 0, stream>>>(part, bproj, (float*)d_out);
}

// Round 4
// 246.824 us; speedup vs baseline: 1.8527x; 1.0769x over previous
//
#include <hip/hip_runtime.h>

// Fused attention block: x@Wqkv^T -> rotary -> flash attn -> @Wproj^T + b
// B=1 N=2048 DIM=128 HEADS=32 D=256 ROT=64, fp32 in/out, bf16 MFMA internals.

typedef unsigned short u16;
typedef unsigned int u32;
typedef __attribute__((ext_vector_type(8))) u16 u16x8;
typedef __attribute__((ext_vector_type(8))) __bf16 bf16x8;
typedef __attribute__((ext_vector_type(4))) float f32x4;
typedef __attribute__((ext_vector_type(4))) u32 u32x4;
typedef __attribute__((ext_vector_type(2))) u32 u32x2;

#define DEV static __device__ __forceinline__

DEV u16 f2b(float f) {                 // native RNE convert (v_cvt_pk-able)
  __bf16 h = (__bf16)f;
  return __builtin_bit_cast(u16, h);
}
DEV float b2f(u16 b) {
  u32 u = ((u32)b) << 16;
  return __builtin_bit_cast(float, u);
}
DEV u32 pk2(float a, float b) { return (u32)f2b(a) | ((u32)f2b(b) << 16); }

DEV f32x4 mfma16(u16x8 a, u16x8 b, f32x4 c) {
  return __builtin_amdgcn_mfma_f32_16x16x32_bf16(
      __builtin_bit_cast(bf16x8, a), __builtin_bit_cast(bf16x8, b), c, 0, 0, 0);
}

// XOR swizzle for the GEMM kernels (rowBytes >= 128).
DEV int swz(int row, int kelem, int rowBytes) {
  return row * rowBytes + ((kelem * 2) ^ ((row & 7) << 4));
}

// global -> LDS DMA, 16B per lane. LDS dest = (wave-uniform) l + lane*16.
DEV void dma16(const void* g, void* l) {
  __builtin_amdgcn_global_load_lds(
      (const __attribute__((address_space(1))) void*)g,
      (__attribute__((address_space(3))) void*)l, 16, 0, 0);
}

// ---------------- kernel 0: fp32 -> bf16 convert ----------------
__global__ __launch_bounds__(256) void k_cvt(const float* __restrict__ src,
                                             u16* __restrict__ dst, int n8) {
  int i = blockIdx.x * 256 + threadIdx.x;
  if (i >= n8) return;
  const float4* s = (const float4*)src;
  float4 a = s[i * 2], b = s[i * 2 + 1];
  u16x8 o;
  o[0] = f2b(a.x); o[1] = f2b(a.y); o[2] = f2b(a.z); o[3] = f2b(a.w);
  o[4] = f2b(b.x); o[5] = f2b(b.y); o[6] = f2b(b.z); o[7] = f2b(b.w);
  *(u16x8*)(dst + (size_t)i * 8) = o;
}

// ---------------- kernel 1: QKV GEMM (M=2048,N=24576,K=128) ----------------
// Q,K written [h][n][256] (Q pre-scaled by SCALE*log2e); V^T written [h][d][n].
__global__ __launch_bounds__(256) void k_qkv(const u16* __restrict__ xb,
                                             const u16* __restrict__ wb,
                                             u16* __restrict__ qw,
                                             u16* __restrict__ kw,
                                             u16* __restrict__ vw) {
  __shared__ char lds[65536];  // W tile [128][128] @0, x tile [128][128] @32768
  const int tid = threadIdx.x;
  const int rt = blockIdx.x % 192, nt = blockIdx.x / 192;
  const int r0 = rt * 128, n0 = nt * 128;
#pragma unroll
  for (int p = 0; p < 8; ++p) {
    int row = p * 16 + (tid >> 4);
    int k0 = (tid & 15) * 8;
    *(u16x8*)(lds + swz(row, k0, 256)) =
        *(const u16x8*)(wb + (size_t)(r0 + row) * 128 + k0);
    *(u16x8*)(lds + 32768 + swz(row, k0, 256)) =
        *(const u16x8*)(xb + (size_t)(n0 + row) * 128 + k0);
  }
  __syncthreads();
  const int wid = tid >> 6, lane = tid & 63, lq = lane & 15, g = lane >> 4;
  const int wr = wid >> 1, wn = wid & 1;
  const bool isV = (r0 >= 16384);
  f32x4 acc[4][4] = {};
#pragma unroll
  for (int ks = 0; ks < 4; ++ks) {
    u16x8 wa[4], xa[4];
#pragma unroll
    for (int i = 0; i < 4; ++i) {
      int rw = wr * 64 + i * 16 + lq;
      wa[i] = *(const u16x8*)(lds + swz(rw, ks * 32 + g * 8, 256));
      int rx = wn * 64 + i * 16 + lq;
      xa[i] = *(const u16x8*)(lds + 32768 + swz(rx, ks * 32 + g * 8, 256));
    }
    if (!isV) {
#pragma unroll
      for (int i = 0; i < 4; ++i)
#pragma unroll
        for (int j = 0; j < 4; ++j) acc[i][j] = mfma16(wa[i], xa[j], acc[i][j]);
    } else {
#pragma unroll
      for (int i = 0; i < 4; ++i)
#pragma unroll
        for (int j = 0; j < 4; ++j) acc[i][j] = mfma16(xa[j], wa[i], acc[i][j]);
    }
  }
  const float SMQ = 0.08838834764831845f * 1.4426950408889634f;
  if (!isV) {
#pragma unroll
    for (int i = 0; i < 4; ++i) {
      int rb = r0 + wr * 64 + i * 16 + g * 4;
      u16* dst0 = (rb >= 8192) ? kw : qw;
      float scl = (rb >= 8192) ? 1.0f : SMQ;   // fold softmax scale into Q
      int hd = rb & 8191;
      int h = hd >> 8, db = hd & 255;
#pragma unroll
      for (int j = 0; j < 4; ++j) {
        int n = n0 + wn * 64 + j * 16 + lq;
        u32x2 pk;
        pk.x = pk2(acc[i][j][0] * scl, acc[i][j][1] * scl);
        pk.y = pk2(acc[i][j][2] * scl, acc[i][j][3] * scl);
        *(u32x2*)(dst0 + ((size_t)h * 2048 + n) * 256 + db) = pk;
      }
    }
  } else {
#pragma unroll
    for (int i = 0; i < 4; ++i) {
      int rc = r0 - 16384 + wr * 64 + i * 16 + lq;
      int h = rc >> 8, d = rc & 255;
#pragma unroll
      for (int j = 0; j < 4; ++j) {
        int nb = n0 + wn * 64 + j * 16 + g * 4;
        u32x2 pk;
        pk.x = pk2(acc[i][j][0], acc[i][j][1]);
        pk.y = pk2(acc[i][j][2], acc[i][j][3]);
        *(u32x2*)(vw + ((size_t)h * 256 + d) * 2048 + nb) = pk;
      }
    }
  }
}

// ---------------- kernel 2: rotary (in-place on Q,K, first 64 dims) --------
__global__ __launch_bounds__(256) void k_rope(u16* __restrict__ qw,
                                              u16* __restrict__ kw,
                                              const float* __restrict__ fr) {
  int idx = blockIdx.x * 256 + threadIdx.x;  // 2*32*2048*4 = 524288
  int seg = idx & 3;
  int n = (idx >> 2) & 2047;
  int h = (idx >> 13) & 31;
  u16* base = ((idx >> 18) ? kw : qw) + ((size_t)h * 2048 + n) * 256 + seg * 8;
  u16x8 lo = *(const u16x8*)base;
  u16x8 hi = *(const u16x8*)(base + 32);
  const float* f = fr + n * 64 + seg * 8;
  u16x8 nlo, nhi;
#pragma unroll
  for (int e = 0; e < 8; ++e) {
    float fl = f[e], fh = f[e + 32];
    float sl, cl, sh, ch;
    __sincosf(fl, &sl, &cl);
    __sincosf(fh, &sh, &ch);
    float a = b2f(lo[e]), b = b2f(hi[e]);
    nlo[e] = f2b(a * cl - b * sl);
    nhi[e] = f2b(b * ch + a * sh);
  }
  *(u16x8*)base = nlo;
  *(u16x8*)(base + 32) = nhi;
}

// ---------------- kernel 3: flash attention ----------------
// QBLK=128 (4 waves x 32 q), KVBLK=32, 2 blocks/CU, double-buffered LDS via
// global_load_lds. LDS holds K/V in MFMA-SLOT order: slot = 1KB = one wave
// read at (base + lane*16 + const-immediate). Conflict-free, zero addr VALU.
// Swapped QK^T: S^T = mfma(K, Q) so col = q is lane-local for softmax.
__global__ __launch_bounds__(256, 2) void k_attn(const u16* __restrict__ qw,
                                                 const u16* __restrict__ kw,
                                                 const u16* __restrict__ vw,
                                                 u16* __restrict__ ow) {
  // per buf (32KB): K slots [16][1KB] @0 ; V slots [16][1KB] @16384
  // K slot s=f*8+ds, lane l: K[kv0+f*16+(l&15)][ds*32+(l>>4)*8 ..+7]
  // V slot u=di,     lane l: V^T[di*16+(l&15)][kv0+(l>>4)*8 ..+7]
  __shared__ char lds[65536];
  const int tid = threadIdx.x;
  const int h = blockIdx.x & 31;   // all 16 q-blocks of head h -> XCD h%8
  const int qb = blockIdx.x >> 5;
  const int wid = tid >> 6, lane = tid & 63, lq = lane & 15, g = lane >> 4;
  const int q0 = qb * 128 + wid * 32;
  const int lane16 = lane * 16;

  const u16* kbase = kw + (size_t)h * 2048 * 256;
  const u16* vbase = vw + (size_t)h * 256 * 2048;

  // per-lane DMA source element-offsets; wave w fills slots w*4 .. w*4+3
  int koff[4], voff[4];
#pragma unroll
  for (int i = 0; i < 4; ++i) {
    int s = wid * 4 + i;
    koff[i] = ((s >> 3) * 16 + lq) * 256 + (s & 7) * 32 + g * 8;
    voff[i] = (s * 16 + lq) * 2048 + g * 8;
  }

  // ---- Q fragments: 32 q-rows (2 frags of 16) in registers ----
  u16x8 qf[2][8];
  {
    const u16* q0p = qw + ((size_t)h * 2048 + q0 + lq) * 256;
#pragma unroll
    for (int ds = 0; ds < 8; ++ds) {
      qf[0][ds] = *(const u16x8*)(q0p + ds * 32 + g * 8);
      qf[1][ds] = *(const u16x8*)(q0p + 16 * 256 + ds * 32 + g * 8);
    }
  }

  f32x4 oacc[2][16] = {};
  float mrun[2] = {-1e30f, -1e30f}, lrun[2] = {0.f, 0.f};

#define STAGE(T)                                                     \
  {                                                                  \
    const int kv0 = (T) * 32;                                        \
    char* kb_ = lds + ((T) & 1) * 32768;                             \
    _Pragma("unroll") for (int i = 0; i < 4; ++i) {                  \
      dma16(kbase + (size_t)kv0 * 256 + koff[i],                     \
            kb_ + (wid * 4 + i) * 1024);                             \
      dma16(vbase + kv0 + voff[i],                                   \
            kb_ + 16384 + (wid * 4 + i) * 1024);                     \
    }                                                                \
  }

  STAGE(0);

  for (int t = 0; t < 64; ++t) {
    if (t < 63) {
      STAGE(t + 1);
      asm volatile("s_waitcnt vmcnt(8)" ::: "memory");
    } else {
      asm volatile("s_waitcnt vmcnt(0)" ::: "memory");
    }
    __builtin_amdgcn_s_barrier();
    asm volatile("" ::: "memory");

    const char* kb = lds + (t & 1) * 32768;

    // ---- S^T = K * Q^T ----
    f32x4 sa[2][2] = {};
    __builtin_amdgcn_s_setprio(1);
#pragma unroll
    for (int ds = 0; ds < 8; ++ds) {
#pragma unroll
      for (int f = 0; f < 2; ++f) {
        u16x8 ka = *(const u16x8*)(kb + lane16 + (f * 8 + ds) * 1024);
        sa[0][f] = mfma16(ka, qf[0][ds], sa[0][f]);
        sa[1][f] = mfma16(ka, qf[1][ds], sa[1][f]);
      }
    }
    __builtin_amdgcn_s_setprio(0);

    // ---- online softmax (log2 domain, scale pre-folded), defer-max ----
    u32 pk[2][2][2];
#pragma unroll
    for (int c = 0; c < 2; ++c) {
      float mt = -1e30f;
#pragma unroll
      for (int f = 0; f < 2; ++f)
#pragma unroll
        for (int r = 0; r < 4; ++r) mt = fmaxf(mt, sa[c][f][r]);
      mt = fmaxf(mt, __shfl_xor(mt, 16));
      mt = fmaxf(mt, __shfl_xor(mt, 32));
      bool skip = __all(mt - mrun[c] <= 8.0f);
      if (!skip) {
        float mnew = fmaxf(mrun[c], mt);
        float corr = exp2f(mrun[c] - mnew);
        lrun[c] *= corr;
#pragma unroll
        for (int di = 0; di < 16; ++di) {
          oacc[c][di][0] *= corr; oacc[c][di][1] *= corr;
          oacc[c][di][2] *= corr; oacc[c][di][3] *= corr;
        }
        mrun[c] = mnew;
      }
      float lt = 0.f;
#pragma unroll
      for (int f = 0; f < 2; ++f) {
        float p0 = exp2f(sa[c][f][0] - mrun[c]);
        float p1 = exp2f(sa[c][f][1] - mrun[c]);
        float p2 = exp2f(sa[c][f][2] - mrun[c]);
        float p3 = exp2f(sa[c][f][3] - mrun[c]);
        lt += (p0 + p1) + (p2 + p3);
        pk[c][f][0] = pk2(p0, p1);
        pk[c][f][1] = pk2(p2, p3);
      }
      lt += __shfl_xor(lt, 16);
      lt += __shfl_xor(lt, 32);
      lrun[c] += lt;
    }

    // ---- build P B-frags via shuffles (u32 pairs -> bit_cast) ----
    u16x8 pb[2];
#pragma unroll
    for (int c = 0; c < 2; ++c) {
      u32x4 bu;
#pragma unroll
      for (int tt = 0; tt < 4; ++tt) {
        int src = (2 * (g & 1) + (tt >> 1)) * 16 + lq;
        u32 vlo = (u32)__shfl((int)pk[c][0][tt & 1], src);
        u32 vhi = (u32)__shfl((int)pk[c][1][tt & 1], src);
        bu[tt] = (g < 2) ? vlo : vhi;
      }
      pb[c] = __builtin_bit_cast(u16x8, bu);
    }

    // ---- PV: O^T += V^T * P^T ----
    __builtin_amdgcn_s_setprio(1);
#pragma unroll
    for (int di = 0; di < 16; ++di) {
      u16x8 va = *(const u16x8*)(kb + 16384 + lane16 + di * 1024);
      oacc[0][di] = mfma16(va, pb[0], oacc[0][di]);
      oacc[1][di] = mfma16(va, pb[1], oacc[1][di]);
    }
    __builtin_amdgcn_s_setprio(0);

    __builtin_amdgcn_s_barrier();
    asm volatile("" ::: "memory");
  }
#undef STAGE

#pragma unroll
  for (int c = 0; c < 2; ++c) {
    float inv = 1.0f / lrun[c];
    u16* orow = ow + (size_t)(q0 + c * 16 + lq) * 8192 + h * 256;
#pragma unroll
    for (int di = 0; di < 16; ++di) {
      u32x2 o2;
      o2.x = pk2(oacc[c][di][0] * inv, oacc[c][di][1] * inv);
      o2.y = pk2(oacc[c][di][2] * inv, oacc[c][di][3] * inv);
      *(u32x2*)(orow + di * 16 + g * 4) = o2;
    }
  }
}

// ---------------- kernel 4: out-proj (split-K=8, fp32 partials) ------------
__global__ __launch_bounds__(256) void k_proj(const u16* __restrict__ ow,
                                              const u16* __restrict__ wp,
                                              float* __restrict__ part) {
  __shared__ char lds[49152];  // O tile [64][128] @0, Wp tile [128][128] @16384
  const int tid = threadIdx.x;
  const int nt = blockIdx.x >> 3, kc = blockIdx.x & 7;
  const int n0 = nt * 64, kb = kc * 1024;
  const int wid = tid >> 6, lane = tid & 63, lq = lane & 15, g = lane >> 4;
  f32x4 acc[8] = {};
  for (int kt = 0; kt < 8; ++kt) {
    int kk = kb + kt * 128;
#pragma unroll
    for (int p = 0; p < 4; ++p) {
      int nr = p * 16 + (tid >> 4);
      int k0 = (tid & 15) * 8;
      *(u16x8*)(lds + swz(nr, k0, 256)) =
          *(const u16x8*)(ow + (size_t)(n0 + nr) * 8192 + kk + k0);
    }
#pragma unroll
    for (int p = 0; p < 8; ++p) {
      int er = p * 16 + (tid >> 4);
      int k0 = (tid & 15) * 8;
      *(u16x8*)(lds + 16384 + swz(er, k0, 256)) =
          *(const u16x8*)(wp + (size_t)er * 8192 + kk + k0);
    }
    __syncthreads();
#pragma unroll
    for (int ks = 0; ks < 4; ++ks) {
      int nr = wid * 16 + lq;
      u16x8 oa = *(const u16x8*)(lds + swz(nr, ks * 32 + g * 8, 256));
#pragma unroll
      for (int ef = 0; ef < 8; ++ef) {
        int er = ef * 16 + lq;
        u16x8 wf = *(const u16x8*)(lds + 16384 + swz(er, ks * 32 + g * 8, 256));
        acc[ef] = mfma16(oa, wf, acc[ef]);
      }
    }
    __syncthreads();
  }
  float* pb = part + (size_t)kc * 262144;
#pragma unroll
  for (int ef = 0; ef < 8; ++ef)
#pragma unroll
    for (int r = 0; r < 4; ++r) {
      int n = n0 + wid * 16 + g * 4 + r;
      pb[n * 128 + ef * 16 + lq] = acc[ef][r];
    }
}

// ---------------- kernel 5: reduce partials + bias ----------------
__global__ __launch_bounds__(256) void k_reduce(const float* __restrict__ part,
                                                const float* __restrict__ bias,
                                                float* __restrict__ out) {
  int i = blockIdx.x * 256 + threadIdx.x;  // 262144 total, grid exact
  float s = bias[i & 127];
#pragma unroll
  for (int c = 0; c < 8; ++c) s += part[(size_t)c * 262144 + i];
  out[i] = s;
}

extern "C" void kernel_launch(void* const* d_in, const int* in_sizes, int n_in,
                              void* d_out, int out_size, void* d_ws, size_t ws_size,
                              hipStream_t stream) {
  const float* x = (const float*)d_in[0];
  const float* wqkv = (const float*)d_in[1];
  const float* wproj = (const float*)d_in[2];
  const float* bproj = (const float*)d_in[3];
  const float* rope = (const float*)d_in[4];
  char* ws = (char*)d_ws;
  u16* xb    = (u16*)(ws);                    // 512 KiB
  u16* wqkvb = (u16*)(ws + 524288);           // 6 MiB
  u16* wpb   = (u16*)(ws + 6815744);          // 2 MiB
  u16* qw    = (u16*)(ws + 8912896);          // 32 MiB [h][n][256]
  u16* kw    = (u16*)(ws + 42467328);         // 32 MiB [h][n][256]
  u16* vw    = (u16*)(ws + 76021760);         // 32 MiB [h][d][n] (V^T)
  u16* owv   = (u16*)(ws + 109576192);        // 32 MiB [n][8192]
  float* part = (float*)(ws + 8912896);       // 8 MiB, overlays dead qw

  k_cvt<<<128, 256, 0, stream>>>(x, xb, 32768);
  k_cvt<<<1536, 256, 0, stream>>>(wqkv, wqkvb, 393216);
  k_cvt<<<512, 256, 0, stream>>>(wproj, wpb, 131072);
  k_qkv<<<3072, 256, 0, stream>>>(xb, wqkvb, qw, kw, vw);
  k_rope<<<2048, 256, 0, stream>>>(qw, kw, rope);
  k_attn<<<512, 256, 0, stream>>>(qw, kw, vw, owv);
  k_proj<<<256, 256, 0, stream>>>(owv, wpb, part);
  k_reduce<<<1024, 256, 0, stream>>>(part, bproj, (float*)d_out);
}

// Round 9
// 229.420 us; speedup vs baseline: 1.9932x; 1.0759x over previous
//
#include <hip/hip_runtime.h>

// Fused attention block: x@Wqkv^T -> rotary -> flash attn -> @Wproj^T + b
// B=1 N=2048 DIM=128 HEADS=32 D=256 ROT=64, fp32 in/out, bf16 MFMA internals.

typedef unsigned short u16;
typedef unsigned int u32;
typedef __attribute__((ext_vector_type(8))) u16 u16x8;
typedef __attribute__((ext_vector_type(8))) __bf16 bf16x8;
typedef __attribute__((ext_vector_type(4))) float f32x4;
typedef __attribute__((ext_vector_type(16))) float f32x16;
typedef __attribute__((ext_vector_type(4))) u32 u32x4;
typedef __attribute__((ext_vector_type(2))) u32 u32x2;

#define DEV static __device__ __forceinline__

DEV u16 f2b(float f) {                 // native RNE convert (v_cvt_pk-able)
  __bf16 h = (__bf16)f;
  return __builtin_bit_cast(u16, h);
}
DEV float b2f(u16 b) {
  u32 u = ((u32)b) << 16;
  return __builtin_bit_cast(float, u);
}
DEV u32 pk2(float a, float b) { return (u32)f2b(a) | ((u32)f2b(b) << 16); }

DEV f32x4 mfma16(u16x8 a, u16x8 b, f32x4 c) {
  return __builtin_amdgcn_mfma_f32_16x16x32_bf16(
      __builtin_bit_cast(bf16x8, a), __builtin_bit_cast(bf16x8, b), c, 0, 0, 0);
}
DEV f32x16 mfma32(u16x8 a, u16x8 b, f32x16 c) {
  return __builtin_amdgcn_mfma_f32_32x32x16_bf16(
      __builtin_bit_cast(bf16x8, a), __builtin_bit_cast(bf16x8, b), c, 0, 0, 0);
}

// XOR swizzle for the GEMM kernels (rowBytes >= 128).
DEV int swz(int row, int kelem, int rowBytes) {
  return row * rowBytes + ((kelem * 2) ^ ((row & 7) << 4));
}

// global -> LDS DMA, 16B per lane. LDS dest = (wave-uniform) l + lane*16.
DEV void dma16(const void* g, void* l) {
  __builtin_amdgcn_global_load_lds(
      (const __attribute__((address_space(1))) void*)g,
      (__attribute__((address_space(3))) void*)l, 16, 0, 0);
}

// ---------------- kernel 0: fp32 -> bf16 convert ----------------
__global__ __launch_bounds__(256) void k_cvt(const float* __restrict__ src,
                                             u16* __restrict__ dst, int n8) {
  int i = blockIdx.x * 256 + threadIdx.x;
  if (i >= n8) return;
  const float4* s = (const float4*)src;
  float4 a = s[i * 2], b = s[i * 2 + 1];
  u16x8 o;
  o[0] = f2b(a.x); o[1] = f2b(a.y); o[2] = f2b(a.z); o[3] = f2b(a.w);
  o[4] = f2b(b.x); o[5] = f2b(b.y); o[6] = f2b(b.z); o[7] = f2b(b.w);
  *(u16x8*)(dst + (size_t)i * 8) = o;
}

// ---------------- kernel 1: QKV GEMM (M=2048,N=24576,K=128) ----------------
// Q,K written [h][n][256] (Q pre-scaled by SCALE*log2e); V^T written [h][d][n].
__global__ __launch_bounds__(256) void k_qkv(const u16* __restrict__ xb,
                                             const u16* __restrict__ wb,
                                             u16* __restrict__ qw,
                                             u16* __restrict__ kw,
                                             u16* __restrict__ vw) {
  __shared__ char lds[65536];  // W tile [128][128] @0, x tile [128][128] @32768
  const int tid = threadIdx.x;
  const int rt = blockIdx.x % 192, nt = blockIdx.x / 192;
  const int r0 = rt * 128, n0 = nt * 128;
#pragma unroll
  for (int p = 0; p < 8; ++p) {
    int row = p * 16 + (tid >> 4);
    int k0 = (tid & 15) * 8;
    *(u16x8*)(lds + swz(row, k0, 256)) =
        *(const u16x8*)(wb + (size_t)(r0 + row) * 128 + k0);
    *(u16x8*)(lds + 32768 + swz(row, k0, 256)) =
        *(const u16x8*)(xb + (size_t)(n0 + row) * 128 + k0);
  }
  __syncthreads();
  const int wid = tid >> 6, lane = tid & 63, lq = lane & 15, g = lane >> 4;
  const int wr = wid >> 1, wn = wid & 1;
  const bool isV = (r0 >= 16384);
  f32x4 acc[4][4] = {};
#pragma unroll
  for (int ks = 0; ks < 4; ++ks) {
    u16x8 wa[4], xa[4];
#pragma unroll
    for (int i = 0; i < 4; ++i) {
      int rw = wr * 64 + i * 16 + lq;
      wa[i] = *(const u16x8*)(lds + swz(rw, ks * 32 + g * 8, 256));
      int rx = wn * 64 + i * 16 + lq;
      xa[i] = *(const u16x8*)(lds + 32768 + swz(rx, ks * 32 + g * 8, 256));
    }
    if (!isV) {
#pragma unroll
      for (int i = 0; i < 4; ++i)
#pragma unroll
        for (int j = 0; j < 4; ++j) acc[i][j] = mfma16(wa[i], xa[j], acc[i][j]);
    } else {
#pragma unroll
      for (int i = 0; i < 4; ++i)
#pragma unroll
        for (int j = 0; j < 4; ++j) acc[i][j] = mfma16(xa[j], wa[i], acc[i][j]);
    }
  }
  const float SMQ = 0.08838834764831845f * 1.4426950408889634f;
  if (!isV) {
#pragma unroll
    for (int i = 0; i < 4; ++i) {
      int rb = r0 + wr * 64 + i * 16 + g * 4;
      u16* dst0 = (rb >= 8192) ? kw : qw;
      float scl = (rb >= 8192) ? 1.0f : SMQ;   // fold softmax scale into Q
      int hd = rb & 8191;
      int h = hd >> 8, db = hd & 255;
#pragma unroll
      for (int j = 0; j < 4; ++j) {
        int n = n0 + wn * 64 + j * 16 + lq;
        u32x2 pk;
        pk.x = pk2(acc[i][j][0] * scl, acc[i][j][1] * scl);
        pk.y = pk2(acc[i][j][2] * scl, acc[i][j][3] * scl);
        *(u32x2*)(dst0 + ((size_t)h * 2048 + n) * 256 + db) = pk;
      }
    }
  } else {
#pragma unroll
    for (int i = 0; i < 4; ++i) {
      int rc = r0 - 16384 + wr * 64 + i * 16 + lq;
      int h = rc >> 8, d = rc & 255;
#pragma unroll
      for (int j = 0; j < 4; ++j) {
        int nb = n0 + wn * 64 + j * 16 + g * 4;
        u32x2 pk;
        pk.x = pk2(acc[i][j][0], acc[i][j][1]);
        pk.y = pk2(acc[i][j][2], acc[i][j][3]);
        *(u32x2*)(vw + ((size_t)h * 256 + d) * 2048 + nb) = pk;
      }
    }
  }
}

// ---------------- kernel 2: rotary (in-place on Q,K, first 64 dims) --------
__global__ __launch_bounds__(256) void k_rope(u16* __restrict__ qw,
                                              u16* __restrict__ kw,
                                              const float* __restrict__ fr) {
  int idx = blockIdx.x * 256 + threadIdx.x;  // 2*32*2048*4 = 524288
  int seg = idx & 3;
  int n = (idx >> 2) & 2047;
  int h = (idx >> 13) & 31;
  u16* base = ((idx >> 18) ? kw : qw) + ((size_t)h * 2048 + n) * 256 + seg * 8;
  u16x8 lo = *(const u16x8*)base;
  u16x8 hi = *(const u16x8*)(base + 32);
  const float* f = fr + n * 64 + seg * 8;
  u16x8 nlo, nhi;
#pragma unroll
  for (int e = 0; e < 8; ++e) {
    float fl = f[e], fh = f[e + 32];
    float sl, cl, sh, ch;
    __sincosf(fl, &sl, &cl);
    __sincosf(fh, &sh, &ch);
    float a = b2f(lo[e]), b = b2f(hi[e]);
    nlo[e] = f2b(a * cl - b * sl);
    nhi[e] = f2b(b * ch + a * sh);
  }
  *(u16x8*)base = nlo;
  *(u16x8*)(base + 32) = nhi;
}

// ---------------- kernel 3: flash attention ----------------
// QBLK=256 (8 waves x 32 q), KVBLK=32, 1 block/CU, 3 LDS buffers (96KB),
// ONE barrier per tile, stage 2-ahead via global_load_lds, vmcnt(4).
// 32x32x16 MFMA; swapped QK^T (S^T = mfma32(K,Q)) so each lane holds 16
// S-values of ONE q (col=lane&31). ALL cross-half exchange via proven
// __shfl_xor(.,32) (permlane semantics burned us in r5-r7).
// LDS slot order: slot = 1KB = one wave-read at (base + lane*16 + imm).
__global__ __launch_bounds__(512, 2) void k_attn(const u16* __restrict__ qw,
                                                 const u16* __restrict__ kw,
                                                 const u16* __restrict__ vw,
                                                 u16* __restrict__ ow) {
  // per buf (32KB): K slots dt=0..15 [1KB each] @0 ; V slots (dt,kvq) @16384
  // K slot dt, lane l:      K[kv0+(l&31)][dt*16 + (l>>5)*8 ..+7]
  // V slot (dt,kvq), lane l: V^T[dt*32+(l&31)][kv0+kvq*16+(l>>5)*8 ..+7]
  __shared__ char lds[98304];
  const int tid = threadIdx.x;
  const int h = blockIdx.x & 31;   // head's 8 q-blocks -> same XCD (h%8)
  const int qb = blockIdx.x >> 5;
  const int wid = tid >> 6, lane = tid & 63;
  const int l31 = lane & 31, h2 = lane >> 5;
  const int q0w = qb * 256 + wid * 32;
  const int lane16 = lane * 16;

  const u16* kbase = kw + (size_t)h * 2048 * 256;
  const u16* vbase = vw + (size_t)h * 256 * 2048;

  // staging: 32 slots/tile, wave w owns slots w*4..w*4+3 (waves 0-3: K, 4-7: V)
  const bool isK = (wid < 4);
  const int dstslot = isK ? wid * 4 : 16 + (wid - 4) * 4;
  int off[4];
#pragma unroll
  for (int i = 0; i < 4; ++i) {
    if (isK) {
      int s = wid * 4 + i;
      off[i] = l31 * 256 + s * 16 + h2 * 8;
    } else {
      int u = (wid - 4) * 4 + i;
      off[i] = ((u >> 1) * 32 + l31) * 2048 + (u & 1) * 16 + h2 * 8;
    }
  }

  // Q fragments: lane l holds Q[q0w+(l&31)][dt*16+(l>>5)*8 ..+7], dt=0..15
  u16x8 qf[16];
  {
    const u16* qp = qw + ((size_t)h * 2048 + q0w + l31) * 256 + h2 * 8;
#pragma unroll
    for (int dt = 0; dt < 16; ++dt) qf[dt] = *(const u16x8*)(qp + dt * 16);
  }

  f32x16 oacc[8] = {};
  float mrun = -1e30f, lrun = 0.f;

#define STAGE(T, BUF)                                               \
  {                                                                 \
    const int kv0_ = (T) * 32;                                      \
    char* b_ = lds + (BUF) * 32768;                                 \
    if (isK) {                                                      \
      _Pragma("unroll") for (int i = 0; i < 4; ++i)                 \
          dma16(kbase + (size_t)kv0_ * 256 + off[i],                \
                b_ + (dstslot + i) * 1024);                         \
    } else {                                                        \
      _Pragma("unroll") for (int i = 0; i < 4; ++i)                 \
          dma16(vbase + kv0_ + off[i], b_ + (dstslot + i) * 1024);  \
    }                                                               \
  }

  STAGE(0, 0);
  STAGE(1, 1);
  int rb = 0, sb = 2;

  for (int t = 0; t < 64; ++t) {
    if (t < 63)
      asm volatile("s_waitcnt vmcnt(4)" ::: "memory");
    else
      asm volatile("s_waitcnt vmcnt(0)" ::: "memory");
    __builtin_amdgcn_s_barrier();
    asm volatile("" ::: "memory");
    if (t < 62) STAGE(t + 2, sb);

    const char* kb = lds + rb * 32768;

    // ---- S^T(32kv x 32q) = K * Q^T over d=256 (16 K-steps) ----
    f32x16 sa = {};
    __builtin_amdgcn_s_setprio(1);
#pragma unroll
    for (int dt = 0; dt < 16; ++dt) {
      u16x8 ka = *(const u16x8*)(kb + dt * 1024 + lane16);
      sa = mfma32(ka, qf[dt], sa);
    }
    __builtin_amdgcn_s_setprio(0);
    // lane layout: q = l&31; reg r: kv = (r&3) + 4*h2 + 8*(r>>2)

    // ---- online softmax (log2 domain; scale folded into Q) ----
    float m8[8];
#pragma unroll
    for (int r = 0; r < 8; ++r) m8[r] = fmaxf(sa[r], sa[r + 8]);
#pragma unroll
    for (int r = 0; r < 4; ++r) m8[r] = fmaxf(m8[r], m8[r + 4]);
    float mt = fmaxf(fmaxf(m8[0], m8[1]), fmaxf(m8[2], m8[3]));
    mt = fmaxf(mt, __shfl_xor(mt, 32));     // cross-half (same q)
    if (!__all(mt - mrun <= 8.0f)) {        // defer-max (T13)
      float mnew = fmaxf(mrun, mt);
      float corr = __builtin_amdgcn_exp2f(mrun - mnew);
      lrun *= corr;
#pragma unroll
      for (int dt = 0; dt < 8; ++dt)
#pragma unroll
        for (int r = 0; r < 16; ++r) oacc[dt][r] *= corr;
      mrun = mnew;
    }
    float p[16];
#pragma unroll
    for (int r = 0; r < 16; ++r)
      p[r] = __builtin_amdgcn_exp2f(sa[r] - mrun);
    float s8[8];
#pragma unroll
    for (int r = 0; r < 8; ++r) s8[r] = p[r] + p[r + 8];
#pragma unroll
    for (int r = 0; r < 4; ++r) s8[r] = s8[r] + s8[r + 4];
    float lt = (s8[0] + s8[1]) + (s8[2] + s8[3]);
    lt += __shfl_xor(lt, 32);
    lrun += lt;

    // ---- P -> two B-frags via shfl_xor(.,32) + per-half select ----
    // pkk[j] pairs: j=0..3 -> kv {0,1},{2,3},{8,9},{10,11} (+4*h2)
    //               j=4..7 -> kv {16,17},{18,19},{24,25},{26,27} (+4*h2)
    // B-frag word w at lane needs P[kv = kvq*16 + 8*h2 + 2w,+1][q].
    u32 pkk[8], xpk[8];
#pragma unroll
    for (int j = 0; j < 8; ++j) pkk[j] = pk2(p[2 * j], p[2 * j + 1]);
#pragma unroll
    for (int j = 0; j < 8; ++j) xpk[j] = (u32)__shfl_xor((int)pkk[j], 32);
    u32x4 b0v, b1v;
    b0v[0] = h2 ? xpk[2] : pkk[0];
    b0v[1] = h2 ? xpk[3] : pkk[1];
    b0v[2] = h2 ? pkk[2] : xpk[0];
    b0v[3] = h2 ? pkk[3] : xpk[1];
    b1v[0] = h2 ? xpk[6] : pkk[4];
    b1v[1] = h2 ? xpk[7] : pkk[5];
    b1v[2] = h2 ? pkk[6] : xpk[4];
    b1v[3] = h2 ? pkk[7] : xpk[5];
    u16x8 pb0 = __builtin_bit_cast(u16x8, b0v);
    u16x8 pb1 = __builtin_bit_cast(u16x8, b1v);

    // ---- PV: O^T(d x q) += V^T * P^T ----
    __builtin_amdgcn_s_setprio(1);
#pragma unroll
    for (int dt = 0; dt < 8; ++dt) {
      u16x8 v0 = *(const u16x8*)(kb + 16384 + (dt * 2) * 1024 + lane16);
      oacc[dt] = mfma32(v0, pb0, oacc[dt]);
      u16x8 v1 = *(const u16x8*)(kb + 16384 + (dt * 2 + 1) * 1024 + lane16);
      oacc[dt] = mfma32(v1, pb1, oacc[dt]);
    }
    __builtin_amdgcn_s_setprio(0);

    rb = (rb == 2) ? 0 : rb + 1;
    sb = (sb == 2) ? 0 : sb + 1;
  }
#undef STAGE

  // ---- epilogue: O^T lane l: q=l&31, d = dt*32 + 8*(r>>2) + (r&3) + 4*h2
  float inv = 1.0f / lrun;
  u16* orow = ow + (size_t)(q0w + l31) * 8192 + h * 256 + h2 * 4;
#pragma unroll
  for (int dt = 0; dt < 8; ++dt)
#pragma unroll
    for (int k = 0; k < 4; ++k) {
      u32x2 o2;
      o2.x = pk2(oacc[dt][4 * k] * inv, oacc[dt][4 * k + 1] * inv);
      o2.y = pk2(oacc[dt][4 * k + 2] * inv, oacc[dt][4 * k + 3] * inv);
      *(u32x2*)(orow + dt * 32 + k * 8) = o2;
    }
}

// ---------------- kernel 4: out-proj (split-K=8, fp32 partials) ------------
__global__ __launch_bounds__(256) void k_proj(const u16* __restrict__ ow,
                                              const u16* __restrict__ wp,
                                              float* __restrict__ part) {
  __shared__ char lds[49152];  // O tile [64][128] @0, Wp tile [128][128] @16384
  const int tid = threadIdx.x;
  const int nt = blockIdx.x >> 3, kc = blockIdx.x & 7;
  const int n0 = nt * 64, kb = kc * 1024;
  const int wid = tid >> 6, lane = tid & 63, lq = lane & 15, g = lane >> 4;
  f32x4 acc[8] = {};
  for (int kt = 0; kt < 8; ++kt) {
    int kk = kb + kt * 128;
#pragma unroll
    for (int p = 0; p < 4; ++p) {
      int nr = p * 16 + (tid >> 4);
      int k0 = (tid & 15) * 8;
      *(u16x8*)(lds + swz(nr, k0, 256)) =
          *(const u16x8*)(ow + (size_t)(n0 + nr) * 8192 + kk + k0);
    }
#pragma unroll
    for (int p = 0; p < 8; ++p) {
      int er = p * 16 + (tid >> 4);
      int k0 = (tid & 15) * 8;
      *(u16x8*)(lds + 16384 + swz(er, k0, 256)) =
          *(const u16x8*)(wp + (size_t)er * 8192 + kk + k0);
    }
    __syncthreads();
#pragma unroll
    for (int ks = 0; ks < 4; ++ks) {
      int nr = wid * 16 + lq;
      u16x8 oa = *(const u16x8*)(lds + swz(nr, ks * 32 + g * 8, 256));
#pragma unroll
      for (int ef = 0; ef < 8; ++ef) {
        int er = ef * 16 + lq;
        u16x8 wf = *(const u16x8*)(lds + 16384 + swz(er, ks * 32 + g * 8, 256));
        acc[ef] = mfma16(oa, wf, acc[ef]);
      }
    }
    __syncthreads();
  }
  float* pb = part + (size_t)kc * 262144;
#pragma unroll
  for (int ef = 0; ef < 8; ++ef)
#pragma unroll
    for (int r = 0; r < 4; ++r) {
      int n = n0 + wid * 16 + g * 4 + r;
      pb[n * 128 + ef * 16 + lq] = acc[ef][r];
    }
}

// ---------------- kernel 5: reduce partials + bias ----------------
__global__ __launch_bounds__(256) void k_reduce(const float* __restrict__ part,
                                                const float* __restrict__ bias,
                                                float* __restrict__ out) {
  int i = blockIdx.x * 256 + threadIdx.x;  // 262144 total, grid exact
  float s = bias[i & 127];
#pragma unroll
  for (int c = 0; c < 8; ++c) s += part[(size_t)c * 262144 + i];
  out[i] = s;
}

extern "C" void kernel_launch(void* const* d_in, const int* in_sizes, int n_in,
                              void* d_out, int out_size, void* d_ws, size_t ws_size,
                              hipStream_t stream) {
  const float* x = (const float*)d_in[0];
  const float* wqkv = (const float*)d_in[1];
  const float* wproj = (const float*)d_in[2];
  const float* bproj = (const float*)d_in[3];
  const float* rope = (const float*)d_in[4];
  char* ws = (char*)d_ws;
  u16* xb    = (u16*)(ws);                    // 512 KiB
  u16* wqkvb = (u16*)(ws + 524288);           // 6 MiB
  u16* wpb   = (u16*)(ws + 6815744);          // 2 MiB
  u16* qw    = (u16*)(ws + 8912896);          // 32 MiB [h][n][256]
  u16* kw    = (u16*)(ws + 42467328);         // 32 MiB [h][n][256]
  u16* vw    = (u16*)(ws + 76021760);         // 32 MiB [h][d][n] (V^T)
  u16* owv   = (u16*)(ws + 109576192);        // 32 MiB [n][8192]
  float* part = (float*)(ws + 8912896);       // 8 MiB, overlays dead qw

  k_cvt<<<128, 256, 0, stream>>>(x, xb, 32768);
  k_cvt<<<1536, 256, 0, stream>>>(wqkv, wqkvb, 393216);
  k_cvt<<<512, 256, 0, stream>>>(wproj, wpb, 131072);
  k_qkv<<<3072, 256, 0, stream>>>(xb, wqkvb, qw, kw, vw);
  k_rope<<<2048, 256, 0, stream>>>(qw, kw, rope);
  k_attn<<<256, 512, 0, stream>>>(qw, kw, vw, owv);
  k_proj<<<256, 256, 0, stream>>>(owv, wpb, part);
  k_reduce<<<1024, 256, 0, stream>>>(part, bproj, (float*)d_out);
}